// Round 4
// baseline (122.401 us; speedup 1.0000x reference)
//
#include <hip/hip_runtime.h>

#define BATCH 4096
#define IN_DIM 512
#define H1DIM 128
#define H2DIM 64
#define DDIM 64
#define NFUNC 2081
#define NFPAD 2112

typedef short bf16x8 __attribute__((ext_vector_type(8)));
typedef float f32x4 __attribute__((ext_vector_type(4)));
#define MFMA(a,b,c) __builtin_amdgcn_mfma_f32_16x16x32_bf16(a,b,c,0,0,0)

#define WSZ1 (H1DIM*IN_DIM)
#define WSZ2 (H2DIM*H1DIM)
#define WSZ3 (DDIM*H2DIM)
#define WSZ4 (H2DIM*DDIM)
#define WSZ5 (H1DIM*H2DIM)
#define WSZ6 (IN_DIM*H1DIM)

__device__ __forceinline__ short f2b(float f) {
    union { float f; unsigned u; } x; x.f = f;
    unsigned r = x.u + 0x7fffu + ((x.u >> 16) & 1u);
    return (short)(r >> 16);
}
__device__ __forceinline__ float b2f(short s) {
    union { unsigned u; float f; } x; x.u = ((unsigned)(unsigned short)s) << 16;
    return x.f;
}
__device__ __forceinline__ void split3f(float v, short& s0, short& s1, short& s2) {
    s0 = f2b(v); float r = v - b2f(s0);
    s1 = f2b(r); float r2 = r - b2f(s1);
    s2 = f2b(r2);
}
__device__ __forceinline__ uint2 pk4(const short* s) {
    union { short s[4]; uint2 u; } z;
    z.s[0] = s[0]; z.s[1] = s[1]; z.s[2] = s[2]; z.s[3] = s[3];
    return z.u;
}

// ---- swizzled LDS tile helpers (row stride RS shorts, byte ^= (r&7)<<4) ----
__device__ __forceinline__ void st_b16(short* t, int RS, int r, int c, short v) {
    int b = (c * 2) ^ ((r & 7) << 4);
    *(short*)((char*)(t + r * RS) + b) = v;
}
__device__ __forceinline__ void st_b64(short* t, int RS, int r, int c0, uint2 v) {
    int b = (c0 * 2) ^ ((r & 7) << 4);
    *(uint2*)((char*)(t + r * RS) + b) = v;
}
__device__ __forceinline__ bf16x8 ld_af(const short* t, int RS, int lane, int kbase) {
    int r = lane & 15;
    int b = ((kbase + (lane >> 4) * 8) * 2) ^ ((r & 7) << 4);
    return *(const bf16x8*)((const char*)(t + r * RS) + b);
}
__device__ __forceinline__ bf16x8 ld_bg(const short* W, int K, int col0, int kbase, int lane) {
    return *(const bf16x8*)(W + (size_t)(col0 + (lane & 15)) * K + kbase + (lane >> 4) * 8);
}

// 8-product split-precision dual layer: primal (f32-grade) + tangent (bf16-grade)
template<int K, int NFRAG>
__device__ __forceinline__ void layer8(const short* a0t, const short* a1t, const short* a2t,
                                       const short* avt, int RS,
                                       const short* W0, int wsz, int col0, int lane,
                                       f32x4* accP, f32x4* accQ, f32x4* accV)
{
    const short* W1 = W0 + wsz;
    const short* W2 = W1 + wsz;
    #pragma unroll
    for (int s = 0; s < K / 32; ++s) {
        bf16x8 f0 = ld_af(a0t, RS, lane, s * 32);
        bf16x8 f1 = ld_af(a1t, RS, lane, s * 32);
        bf16x8 f2 = ld_af(a2t, RS, lane, s * 32);
        bf16x8 fv = ld_af(avt, RS, lane, s * 32);
        #pragma unroll
        for (int nf = 0; nf < NFRAG; ++nf) {
            bf16x8 b0 = ld_bg(W0, K, col0 + nf * 16, s * 32, lane);
            bf16x8 b1 = ld_bg(W1, K, col0 + nf * 16, s * 32, lane);
            bf16x8 b2 = ld_bg(W2, K, col0 + nf * 16, s * 32, lane);
            accP[nf] = MFMA(f0, b0, accP[nf]);
            accQ[nf] = MFMA(f1, b1, accQ[nf]);
            accP[nf] = MFMA(f1, b0, accP[nf]);
            accQ[nf] = MFMA(f0, b1, accQ[nf]);
            accP[nf] = MFMA(f2, b0, accP[nf]);
            accQ[nf] = MFMA(f2, b1, accQ[nf]);
            accP[nf] = MFMA(f0, b2, accP[nf]);
            accQ[nf] = MFMA(f1, b2, accQ[nf]);
            accV[nf] = MFMA(fv, b0, accV[nf]);
        }
    }
}

// epilogue: pre = P+Q+bias; store 3 relu splits + masked tangent bf16
__device__ __forceinline__ void epi_store(short* t0, short* t1, short* t2, short* tv, int RS,
                                          int lane, int col, const f32x4& P, const f32x4& Q,
                                          const f32x4& V, float bb)
{
    #pragma unroll
    for (int q = 0; q < 4; ++q) {
        int row = (lane >> 4) * 4 + q;
        float pre = P[q] + Q[q] + bb;
        float h = fmaxf(pre, 0.f);
        short s0, s1, s2;
        split3f(h, s0, s1, s2);
        st_b16(t0, RS, row, col, s0);
        st_b16(t1, RS, row, col, s1);
        st_b16(t2, RS, row, col, s2);
        st_b16(tv, RS, row, col, pre > 0.f ? f2b(V[q]) : (short)0);
    }
}

// =====================================================================
__global__ void initk(const float* __restrict__ We1, const float* __restrict__ We2,
                      const float* __restrict__ We3, const float* __restrict__ Wd1,
                      const float* __restrict__ Wd2, const float* __restrict__ Wd3,
                      const float* __restrict__ XI, const float* __restrict__ XIm,
                      short* Wb1, short* Wb2, short* Wb3, short* Wb4, short* Wb5, short* Wb6,
                      short* xiT, int2* pk)
{
    int gid = blockIdx.x * blockDim.x + threadIdx.x;
    int nthr = gridDim.x * blockDim.x;
    for (int i = gid; i < WSZ1; i += nthr) { short a,b,c; split3f(We1[i],a,b,c); Wb1[i]=a; Wb1[i+WSZ1]=b; Wb1[i+2*WSZ1]=c; }
    for (int i = gid; i < WSZ2; i += nthr) { short a,b,c; split3f(We2[i],a,b,c); Wb2[i]=a; Wb2[i+WSZ2]=b; Wb2[i+2*WSZ2]=c; }
    for (int i = gid; i < WSZ3; i += nthr) { short a,b,c; split3f(We3[i],a,b,c); Wb3[i]=a; Wb3[i+WSZ3]=b; Wb3[i+2*WSZ3]=c; }
    for (int i = gid; i < WSZ4; i += nthr) { short a,b,c; split3f(Wd1[i],a,b,c); Wb4[i]=a; Wb4[i+WSZ4]=b; Wb4[i+2*WSZ4]=c; }
    for (int i = gid; i < WSZ5; i += nthr) { short a,b,c; split3f(Wd2[i],a,b,c); Wb5[i]=a; Wb5[i+WSZ5]=b; Wb5[i+2*WSZ5]=c; }
    for (int i = gid; i < WSZ6; i += nthr) { short a,b,c; split3f(Wd3[i],a,b,c); Wb6[i]=a; Wb6[i+WSZ6]=b; Wb6[i+2*WSZ6]=c; }
    for (int i = gid; i < DDIM * NFPAD; i += nthr) {
        int c = i / NFPAD, k = i - c * NFPAD;
        float v = (k < NFUNC) ? XI[k * DDIM + c] * XIm[k * DDIM + c] : 0.f;
        xiT[i] = f2b(v);
    }
    for (int f = gid; f < NFPAD; f += nthr) {
        int a, b;
        if (f == 0) { a = 64; b = 64; }
        else if (f <= DDIM) { a = f - 1; b = 64; }
        else if (f < NFUNC) {
            int p = f - 1 - DDIM; int i2 = 0, cum = 0;
            while (cum + (63 - i2) <= p) { cum += 63 - i2; ++i2; }
            a = i2; b = i2 + 1 + (p - cum);
        } else { a = 65; b = 65; }
        pk[f] = make_int2(a, b);
    }
}

// =====================================================================
// grid = 1024 = 256 row-tiles x 4 col-groups. Col-groups replicate
// encoder/SINDy/dec1/dec2 (latency-dominated) and split dec3's N=512.
// tile = bid & 255 so a tile's 4 replicas land on the same XCD (share L2).
__global__ __launch_bounds__(256, 4)
void fused(const float* __restrict__ x, const float* __restrict__ xdot,
           const float* __restrict__ be1, const float* __restrict__ be2,
           const float* __restrict__ be3, const float* __restrict__ bd1,
           const float* __restrict__ bd2, const float* __restrict__ bd3,
           const short* __restrict__ Wb1, const short* __restrict__ Wb2,
           const short* __restrict__ Wb3, const short* __restrict__ Wb4,
           const short* __restrict__ Wb5, const short* __restrict__ Wb6,
           const short* __restrict__ xiT, const int2* __restrict__ pk,
           float* __restrict__ xh, float* __restrict__ dxh, float* __restrict__ zo,
           float* __restrict__ dz, float* __restrict__ dzs)
{
    // LDS 38912 B, regions aliased by lifetime:
    // A @ 0     (8K):  xs0,xs1,xs2,xds (L1 staging) -> g1s0,g1s1,g1s2,u1 (dec1 out)
    // B @ 8192  (16K): h1s0,h1s1,h1s2,v1 -> zf(f32,4.3K, after L2) -> g2s*,u2 (dec2 out)
    // C @ 24576 (8K):  h2s0,h2s1,h2s2,v2 -> th0,th1 (dbuf), dzsb
    // D @ 32768 (6K):  zb0,zb1,zb2
    __shared__ __align__(16) char ldsbuf[38912];
    short* xs0 = (short*)(ldsbuf + 0);
    short* xs1 = (short*)(ldsbuf + 2048);
    short* xs2 = (short*)(ldsbuf + 4096);
    short* xds = (short*)(ldsbuf + 6144);
    short* g1s0 = xs0; short* g1s1 = xs1; short* g1s2 = xs2; short* u1 = xds;
    short* h1s0 = (short*)(ldsbuf + 8192);
    short* h1s1 = (short*)(ldsbuf + 12288);
    short* h1s2 = (short*)(ldsbuf + 16384);
    short* v1   = (short*)(ldsbuf + 20480);
    short* g2s0 = h1s0; short* g2s1 = h1s1; short* g2s2 = h1s2; short* u2 = v1;
    float* zf   = (float*)(ldsbuf + 8192);   // [16][68], alive L3->SINDy only
    short* h2s0 = (short*)(ldsbuf + 24576);
    short* h2s1 = (short*)(ldsbuf + 26624);
    short* h2s2 = (short*)(ldsbuf + 28672);
    short* v2   = (short*)(ldsbuf + 30720);
    short* th0  = h2s0;   // SINDy theta double-buffer (h2 dead after L3)
    short* th1  = h2s1;
    short* dzsb = h2s2;
    short* zb0 = (short*)(ldsbuf + 32768);
    short* zb1 = (short*)(ldsbuf + 34816);
    short* zb2 = (short*)(ldsbuf + 36864);

    const int tid = threadIdx.x, lane = tid & 63, wave = tid >> 6;
    const int tile = blockIdx.x & 255, cg = blockIdx.x >> 8;
    const int row0 = tile * 16;
    const int sr = tid >> 4, sc4 = (tid & 15) * 4;

    // ---------------- encoder L1 (K=512, N=128), streamed in 8 chunks ----------------
    f32x4 accP[2] = {}, accQ[2] = {}, accV[2] = {};
    const float* xrow  = x    + (size_t)(row0 + sr) * IN_DIM + sc4;
    const float* xdrow = xdot + (size_t)(row0 + sr) * IN_DIM + sc4;
    f32x4 pxa[2], pxd[2];
    pxa[0] = *(const f32x4*)xrow;
    pxd[0] = *(const f32x4*)xdrow;
    #pragma unroll
    for (int c = 0; c < 8; ++c) {
        short a0[4], a1[4], a2[4], d0[4];
        #pragma unroll
        for (int e = 0; e < 4; ++e) {
            split3f(pxa[c & 1][e], a0[e], a1[e], a2[e]);
            d0[e] = f2b(pxd[c & 1][e]);
        }
        st_b64(xs0, 64, sr, sc4, pk4(a0));
        st_b64(xs1, 64, sr, sc4, pk4(a1));
        st_b64(xs2, 64, sr, sc4, pk4(a2));
        st_b64(xds, 64, sr, sc4, pk4(d0));
        __syncthreads();
        if (c < 7) {
            pxa[(c + 1) & 1] = *(const f32x4*)(xrow + (c + 1) * 64);
            pxd[(c + 1) & 1] = *(const f32x4*)(xdrow + (c + 1) * 64);
        }
        #pragma unroll
        for (int s = 0; s < 2; ++s) {
            bf16x8 f0 = ld_af(xs0, 64, lane, s * 32);
            bf16x8 f1 = ld_af(xs1, 64, lane, s * 32);
            bf16x8 f2 = ld_af(xs2, 64, lane, s * 32);
            bf16x8 fv = ld_af(xds, 64, lane, s * 32);
            #pragma unroll
            for (int nf = 0; nf < 2; ++nf) {
                int col0 = wave * 32 + nf * 16;
                int kb = c * 64 + s * 32;
                bf16x8 b0 = ld_bg(Wb1, IN_DIM, col0, kb, lane);
                bf16x8 b1 = ld_bg(Wb1 + WSZ1, IN_DIM, col0, kb, lane);
                bf16x8 b2 = ld_bg(Wb1 + 2 * WSZ1, IN_DIM, col0, kb, lane);
                accP[nf] = MFMA(f0, b0, accP[nf]);
                accQ[nf] = MFMA(f1, b1, accQ[nf]);
                accP[nf] = MFMA(f1, b0, accP[nf]);
                accQ[nf] = MFMA(f0, b1, accQ[nf]);
                accP[nf] = MFMA(f2, b0, accP[nf]);
                accQ[nf] = MFMA(f2, b1, accQ[nf]);
                accP[nf] = MFMA(f0, b2, accP[nf]);
                accQ[nf] = MFMA(f1, b2, accQ[nf]);
                accV[nf] = MFMA(fv, b0, accV[nf]);
            }
        }
        __syncthreads();
    }
    #pragma unroll
    for (int nf = 0; nf < 2; ++nf) {
        int col = wave * 32 + nf * 16 + (lane & 15);
        epi_store(h1s0, h1s1, h1s2, v1, 128, lane, col, accP[nf], accQ[nf], accV[nf], be1[col]);
    }
    __syncthreads();

    // ---------------- encoder L2 (K=128, N=64) ----------------
    {
        f32x4 P[1] = {}, Q[1] = {}, V[1] = {};
        layer8<128, 1>(h1s0, h1s1, h1s2, v1, 128, Wb2, WSZ2, wave * 16, lane, P, Q, V);
        int col = wave * 16 + (lane & 15);
        epi_store(h2s0, h2s1, h2s2, v2, 64, lane, col, P[0], Q[0], V[0], be2[col]);
    }
    __syncthreads();   // h2 ready; also: everyone done reading h1/v1 -> zf may overwrite

    // ---------------- encoder L3 (K=64, N=64) -> z, dz ----------------
    {
        f32x4 P[1] = {}, Q[1] = {}, V[1] = {};
        layer8<64, 1>(h2s0, h2s1, h2s2, v2, 64, Wb3, WSZ3, wave * 16, lane, P, Q, V);
        int col = wave * 16 + (lane & 15);
        float bb = be3[col];
        #pragma unroll
        for (int q = 0; q < 4; ++q) {
            int row = (lane >> 4) * 4 + q;
            float pre = P[0][q] + Q[0][q] + bb;
            float hz = fmaxf(pre, 0.f);
            float vz = pre > 0.f ? V[0][q] : 0.f;
            zf[row * 68 + col] = hz;
            short s0, s1, s2;
            split3f(hz, s0, s1, s2);
            st_b16(zb0, 64, row, col, s0);
            st_b16(zb1, 64, row, col, s1);
            st_b16(zb2, 64, row, col, s2);
            if (cg == 0) {
                zo[(size_t)(row0 + row) * DDIM + col] = hz;
                dz[(size_t)(row0 + row) * DDIM + col] = vz;
            }
        }
    }
    if (tid < 32) { int r = tid & 15; zf[r * 68 + 64 + (tid >> 4)] = (tid >> 4) ? 0.f : 1.f; }

    // ---------------- SINDy: dzs = theta(z_f32) @ xi (K=2112, N=64) ----------------
    // Double-buffered theta: 1 sync/chunk; prefetch next xi frags + pk pairs.
    f32x4 sacc = {};
    const int tr = tid & 15, tf = (tid >> 4) * 4;
    bf16x8 cb0 = ld_bg(xiT, NFPAD, wave * 16, 0, lane);
    bf16x8 cb1 = ld_bg(xiT, NFPAD, wave * 16, 32, lane);
    int2 cp0 = pk[tf], cp1 = pk[tf + 1], cp2 = pk[tf + 2], cp3 = pk[tf + 3];
    __syncthreads();   // zf fully written (L3 epilogue + sentinels)
    st_b16(th0, 64, tr, tf + 0, f2b(zf[tr * 68 + cp0.x] * zf[tr * 68 + cp0.y]));
    st_b16(th0, 64, tr, tf + 1, f2b(zf[tr * 68 + cp1.x] * zf[tr * 68 + cp1.y]));
    st_b16(th0, 64, tr, tf + 2, f2b(zf[tr * 68 + cp2.x] * zf[tr * 68 + cp2.y]));
    st_b16(th0, 64, tr, tf + 3, f2b(zf[tr * 68 + cp3.x] * zf[tr * 68 + cp3.y]));
    __syncthreads();   // th0 visible
    for (int ch = 0; ch < 33; ++ch) {
        const short* cur = (ch & 1) ? th1 : th0;
        short* nxt = (ch & 1) ? th0 : th1;
        bf16x8 nb0, nb1;
        int2 np0, np1, np2, np3;
        if (ch < 32) {
            int f0n = (ch + 1) * 64;
            nb0 = ld_bg(xiT, NFPAD, wave * 16, f0n, lane);
            nb1 = ld_bg(xiT, NFPAD, wave * 16, f0n + 32, lane);
            np0 = pk[f0n + tf]; np1 = pk[f0n + tf + 1];
            np2 = pk[f0n + tf + 2]; np3 = pk[f0n + tf + 3];
        }
        bf16x8 a0 = ld_af(cur, 64, lane, 0);
        bf16x8 a1 = ld_af(cur, 64, lane, 32);
        sacc = MFMA(a0, cb0, sacc);
        sacc = MFMA(a1, cb1, sacc);
        if (ch < 32) {
            st_b16(nxt, 64, tr, tf + 0, f2b(zf[tr * 68 + np0.x] * zf[tr * 68 + np0.y]));
            st_b16(nxt, 64, tr, tf + 1, f2b(zf[tr * 68 + np1.x] * zf[tr * 68 + np1.y]));
            st_b16(nxt, 64, tr, tf + 2, f2b(zf[tr * 68 + np2.x] * zf[tr * 68 + np2.y]));
            st_b16(nxt, 64, tr, tf + 3, f2b(zf[tr * 68 + np3.x] * zf[tr * 68 + np3.y]));
            cb0 = nb0; cb1 = nb1;
        }
        __syncthreads();
    }
    {
        int col = wave * 16 + (lane & 15);
        #pragma unroll
        for (int q = 0; q < 4; ++q) {
            int row = (lane >> 4) * 4 + q;
            float v = sacc[q];
            if (cg == 0) dzs[(size_t)(row0 + row) * DDIM + col] = v;
            st_b16(dzsb, 64, row, col, f2b(v));
        }
    }
    __syncthreads();

    // ---------------- decoder L1 (K=64, N=64) ----------------
    {
        f32x4 P[1] = {}, Q[1] = {}, V[1] = {};
        layer8<64, 1>(zb0, zb1, zb2, dzsb, 64, Wb4, WSZ4, wave * 16, lane, P, Q, V);
        int col = wave * 16 + (lane & 15);
        epi_store(g1s0, g1s1, g1s2, u1, 64, lane, col, P[0], Q[0], V[0], bd1[col]);
    }
    __syncthreads();

    // ---------------- decoder L2 (K=64, N=128) ----------------
    {
        f32x4 P[2] = {}, Q[2] = {}, V[2] = {};
        layer8<64, 2>(g1s0, g1s1, g1s2, u1, 64, Wb5, WSZ5, wave * 32, lane, P, Q, V);
        #pragma unroll
        for (int nf = 0; nf < 2; ++nf) {
            int col = wave * 32 + nf * 16 + (lane & 15);
            epi_store(g2s0, g2s1, g2s2, u2, 128, lane, col, P[nf], Q[nf], V[nf], bd2[col]);
        }
    }
    __syncthreads();

    // ---------------- decoder L3 (K=128, this block's N=128 of 512) ----------------
    {
        f32x4 P[2] = {}, Q[2] = {}, V[2] = {};
        layer8<128, 2>(g2s0, g2s1, g2s2, u2, 128, Wb6, WSZ6, cg * 128 + wave * 32, lane, P, Q, V);
        #pragma unroll
        for (int nf = 0; nf < 2; ++nf) {
            int col = cg * 128 + wave * 32 + nf * 16 + (lane & 15);
            float bb = bd3[col];
            #pragma unroll
            for (int q = 0; q < 4; ++q) {
                int row = (lane >> 4) * 4 + q;
                float pre = P[nf][q] + Q[nf][q] + bb;
                xh[(size_t)(row0 + row) * IN_DIM + col] = fmaxf(pre, 0.f);
                dxh[(size_t)(row0 + row) * IN_DIM + col] = pre > 0.f ? V[nf][q] : 0.f;
            }
        }
    }
}

// =====================================================================
extern "C" void kernel_launch(void* const* d_in, const int* in_sizes, int n_in,
                              void* d_out, int out_size, void* d_ws, size_t ws_size,
                              hipStream_t stream)
{
    const float* x    = (const float*)d_in[0];
    const float* xdot = (const float*)d_in[1];
    const float* We1  = (const float*)d_in[2];
    const float* be1  = (const float*)d_in[3];
    const float* We2  = (const float*)d_in[4];
    const float* be2  = (const float*)d_in[5];
    const float* We3  = (const float*)d_in[6];
    const float* be3  = (const float*)d_in[7];
    const float* Wd1  = (const float*)d_in[8];
    const float* bd1  = (const float*)d_in[9];
    const float* Wd2  = (const float*)d_in[10];
    const float* bd2  = (const float*)d_in[11];
    const float* Wd3  = (const float*)d_in[12];
    const float* bd3  = (const float*)d_in[13];
    const float* XI   = (const float*)d_in[14];
    const float* XIm  = (const float*)d_in[15];

    float* out = (float*)d_out;
    float* xh  = out;
    float* dxh = out + (size_t)BATCH * IN_DIM;
    float* zo  = dxh + (size_t)BATCH * IN_DIM;
    float* dz  = zo + (size_t)BATCH * DDIM;
    float* dzs = dz + (size_t)BATCH * DDIM;

    // ws layout: pk, 3-plane bf16 weight splits, xiT
    int2*  pk  = (int2*)d_ws;                      // [2112]
    short* Wb1 = (short*)(pk + NFPAD);
    short* Wb2 = Wb1 + 3 * WSZ1;
    short* Wb3 = Wb2 + 3 * WSZ2;
    short* Wb4 = Wb3 + 3 * WSZ3;
    short* Wb5 = Wb4 + 3 * WSZ4;
    short* Wb6 = Wb5 + 3 * WSZ5;
    short* xiT = Wb6 + 3 * WSZ6;                   // [64][2112]

    initk<<<256, 256, 0, stream>>>(We1, We2, We3, Wd1, Wd2, Wd3, XI, XIm,
                                   Wb1, Wb2, Wb3, Wb4, Wb5, Wb6, xiT, pk);
    fused<<<1024, 256, 0, stream>>>(x, xdot, be1, be2, be3, bd1, bd2, bd3,
                                    Wb1, Wb2, Wb3, Wb4, Wb5, Wb6, xiT, pk,
                                    xh, dxh, zo, dz, dzs);
}

// Round 5
// 70.982 us; speedup vs baseline: 1.7244x; 1.7244x over previous
//
#include <hip/hip_runtime.h>

#define BATCH 4096
#define IN_DIM 512
#define H1DIM 128
#define H2DIM 64
#define DDIM 64
#define NFUNC 2081
#define NFPAD 2112
#define CHUNK 704           // 2112 = 3 * 704
#define KS_PER_CHUNK 22     // 704/32

typedef short bf16x8 __attribute__((ext_vector_type(8)));
typedef float f32x4 __attribute__((ext_vector_type(4)));
#define MFMA(a,b,c) __builtin_amdgcn_mfma_f32_16x16x32_bf16(a,b,c,0,0,0)

#define WSZ1 (H1DIM*IN_DIM)
#define WSZ2 (H2DIM*H1DIM)
#define WSZ3 (DDIM*H2DIM)
#define WSZ4 (H2DIM*DDIM)
#define WSZ5 (H1DIM*H2DIM)
#define WSZ6 (IN_DIM*H1DIM)

__device__ __forceinline__ short f2b(float f) {
    union { float f; unsigned u; } x; x.f = f;
    unsigned r = x.u + 0x7fffu + ((x.u >> 16) & 1u);
    return (short)(r >> 16);
}
__device__ __forceinline__ float b2f(short s) {
    union { unsigned u; float f; } x; x.u = ((unsigned)(unsigned short)s) << 16;
    return x.f;
}
__device__ __forceinline__ void split3f(float v, short& s0, short& s1, short& s2) {
    s0 = f2b(v); float r = v - b2f(s0);
    s1 = f2b(r); float r2 = r - b2f(s1);
    s2 = f2b(r2);
}
__device__ __forceinline__ uint2 pk4(const short* s) {
    union { short s[4]; uint2 u; } z;
    z.s[0] = s[0]; z.s[1] = s[1]; z.s[2] = s[2]; z.s[3] = s[3];
    return z.u;
}

// ---- swizzled LDS tile helpers (row stride RS shorts, byte ^= (r&7)<<4) ----
__device__ __forceinline__ void st_b16(short* t, int RS, int r, int c, short v) {
    int b = (c * 2) ^ ((r & 7) << 4);
    *(short*)((char*)(t + r * RS) + b) = v;
}
__device__ __forceinline__ void st_b64(short* t, int RS, int r, int c0, uint2 v) {
    int b = (c0 * 2) ^ ((r & 7) << 4);
    *(uint2*)((char*)(t + r * RS) + b) = v;
}
__device__ __forceinline__ bf16x8 ld_af(const short* t, int RS, int lane, int kbase) {
    int r = lane & 15;
    int b = ((kbase + (lane >> 4) * 8) * 2) ^ ((r & 7) << 4);
    return *(const bf16x8*)((const char*)(t + r * RS) + b);
}
// packed-frag global load: frag blk = contiguous 64 lanes x 16B (coalesced)
__device__ __forceinline__ bf16x8 ld_bp(const short* P, int blk, int lane) {
    return *(const bf16x8*)(P + ((size_t)blk * 64 + lane) * 8);
}

// 9-MFMA split-precision dual step
__device__ __forceinline__ void mf9(bf16x8 f0, bf16x8 f1, bf16x8 f2, bf16x8 fv,
                                    bf16x8 b0, bf16x8 b1, bf16x8 b2,
                                    f32x4& P, f32x4& Q, f32x4& V) {
    P = MFMA(f0, b0, P); Q = MFMA(f1, b1, Q);
    P = MFMA(f1, b0, P); Q = MFMA(f0, b1, Q);
    P = MFMA(f2, b0, P); Q = MFMA(f2, b1, Q);
    P = MFMA(f0, b2, P); Q = MFMA(f1, b2, Q);
    V = MFMA(fv, b0, V);
}

// layer with LDS A-tiles + packed-frag B
template<int K32, int NFRAG>
__device__ __forceinline__ void layerP(const short* a0t, const short* a1t, const short* a2t,
                                       const short* avt, int RS,
                                       const short* Wp, int NK, int cb0, int lane,
                                       f32x4* P, f32x4* Q, f32x4* V)
{
    #pragma unroll
    for (int ks = 0; ks < K32; ++ks) {
        bf16x8 f0 = ld_af(a0t, RS, lane, ks * 32);
        bf16x8 f1 = ld_af(a1t, RS, lane, ks * 32);
        bf16x8 f2 = ld_af(a2t, RS, lane, ks * 32);
        bf16x8 fv = ld_af(avt, RS, lane, ks * 32);
        #pragma unroll
        for (int nf = 0; nf < NFRAG; ++nf) {
            int blk = (cb0 + nf) * K32 + ks;
            bf16x8 b0 = ld_bp(Wp, blk, lane);
            bf16x8 b1 = ld_bp(Wp + NK, blk, lane);
            bf16x8 b2 = ld_bp(Wp + 2 * NK, blk, lane);
            mf9(f0, f1, f2, fv, b0, b1, b2, P[nf], Q[nf], V[nf]);
        }
    }
}

__device__ __forceinline__ void epi_store(short* t0, short* t1, short* t2, short* tv, int RS,
                                          int lane, int col, const f32x4& P, const f32x4& Q,
                                          const f32x4& V, float bb)
{
    #pragma unroll
    for (int q = 0; q < 4; ++q) {
        int row = (lane >> 4) * 4 + q;
        float pre = P[q] + Q[q] + bb;
        float h = fmaxf(pre, 0.f);
        short s0, s1, s2;
        split3f(h, s0, s1, s2);
        st_b16(t0, RS, row, col, s0);
        st_b16(t1, RS, row, col, s1);
        st_b16(t2, RS, row, col, s2);
        st_b16(tv, RS, row, col, pre > 0.f ? f2b(V[q]) : (short)0);
    }
}

// =====================================================================
template<int K>
__device__ void pack_w(const float* __restrict__ W, short* __restrict__ dst, int NK,
                       int gid, int nthr)
{
    for (int i = gid; i < NK; i += nthr) {
        int c = i / K, k = i % K;       // K is pow2 -> shifts
        int cb = c >> 4, ks = k >> 5;
        int L = (((k >> 3) & 3) << 4) | (c & 15);
        int j = k & 7;
        int idx = ((cb * (K / 32) + ks) * 64 + L) * 8 + j;
        short s0, s1, s2; split3f(W[i], s0, s1, s2);
        dst[idx] = s0; dst[idx + NK] = s1; dst[idx + 2 * NK] = s2;
    }
}

__global__ void initk(const float* __restrict__ x, const float* __restrict__ xdot,
                      const float* __restrict__ We1, const float* __restrict__ We2,
                      const float* __restrict__ We3, const float* __restrict__ Wd1,
                      const float* __restrict__ Wd2, const float* __restrict__ Wd3,
                      const float* __restrict__ XI, const float* __restrict__ XIm,
                      float* __restrict__ xh, float* __restrict__ dxh,
                      short* Wp1, short* Wp2, short* Wp3, short* Wp4, short* Wp5, short* Wp6,
                      short* xiP, int2* pk)
{
    int gid = blockIdx.x * blockDim.x + threadIdx.x;
    int nthr = gridDim.x * blockDim.x;

    // ---- x/xdot split into A-frag layout, stashed in xh/dxh (own-block region) ----
    for (int i = gid; i < (BATCH / 16) * 16 * 64; i += nthr) {   // 262144 frag-octets
        int L = i & 63, ks = (i >> 6) & 15, rb = i >> 10;
        int row = rb * 16 + (L & 15);
        int k0 = ks * 32 + ((L >> 4) << 3);
        const float* px = &x[(size_t)row * IN_DIM + k0];
        const float* pd = &xdot[(size_t)row * IN_DIM + k0];
        union { short s[8]; bf16x8 v; } a0, a1, a2, dv;
        #pragma unroll
        for (int j = 0; j < 8; ++j) {
            split3f(px[j], a0.s[j], a1.s[j], a2.s[j]);
            dv.s[j] = f2b(pd[j]);
        }
        short* bx = (short*)(xh + (size_t)rb * 8192);
        short* bd = (short*)(dxh + (size_t)rb * 8192);
        int off = (ks * 64 + L) * 8;
        *(bf16x8*)(bx + off) = a0.v;
        *(bf16x8*)(bx + 8192 + off) = a1.v;
        *(bf16x8*)(bd + off) = a2.v;
        *(bf16x8*)(bd + 8192 + off) = dv.v;
    }

    pack_w<512>(We1, Wp1, WSZ1, gid, nthr);
    pack_w<128>(We2, Wp2, WSZ2, gid, nthr);
    pack_w<64>(We3, Wp3, WSZ3, gid, nthr);
    pack_w<64>(Wd1, Wp4, WSZ4, gid, nthr);
    pack_w<64>(Wd2, Wp5, WSZ5, gid, nthr);
    pack_w<128>(Wd3, Wp6, WSZ6, gid, nthr);

    // xi_eff packed as B-frags: [cb(4)][ks(66)][lane][j]
    for (int i = gid; i < 4 * 66 * 64; i += nthr) {
        int cb = i / (66 * 64);
        int r = i - cb * (66 * 64);
        int ks = r >> 6, L = r & 63;
        int col = cb * 16 + (L & 15);
        union { short s[8]; bf16x8 v; } w;
        #pragma unroll
        for (int j = 0; j < 8; ++j) {
            int f = ks * 32 + ((L >> 4) << 3) + j;
            float v = (f < NFUNC) ? XI[(size_t)f * DDIM + col] * XIm[(size_t)f * DDIM + col] : 0.f;
            w.s[j] = f2b(v);
        }
        *(bf16x8*)(xiP + (size_t)i * 8) = w.v;
    }

    for (int f = gid; f < NFPAD; f += nthr) {
        int a, b;
        if (f == 0) { a = 64; b = 64; }
        else if (f <= DDIM) { a = f - 1; b = 64; }
        else if (f < NFUNC) {
            int p = f - 1 - DDIM; int i2 = 0, cum = 0;
            while (cum + (63 - i2) <= p) { cum += 63 - i2; ++i2; }
            a = i2; b = i2 + 1 + (p - cum);
        } else { a = 65; b = 65; }
        pk[f] = make_int2(a, b);
    }
}

// =====================================================================
__global__ __launch_bounds__(256, 1)
void fused(const float* __restrict__ be1, const float* __restrict__ be2,
           const float* __restrict__ be3, const float* __restrict__ bd1,
           const float* __restrict__ bd2, const float* __restrict__ bd3,
           const short* __restrict__ Wp1, const short* __restrict__ Wp2,
           const short* __restrict__ Wp3, const short* __restrict__ Wp4,
           const short* __restrict__ Wp5, const short* __restrict__ Wp6,
           const short* __restrict__ xiP, const int2* __restrict__ pk,
           float* __restrict__ xh, float* __restrict__ dxh, float* __restrict__ zo,
           float* __restrict__ dz, float* __restrict__ dzs)
{
    // LDS 37120 B, lifetime-aliased:
    // region A [0,24576): enc h1/v1 (16K) + h2/v2 (8K)  ->  th (22.5K)  ->  g1/u1 (8K) + g2/u2 (16K)
    // region B [24576,37120): zb0,zb1,zb2, dzsb (2K each), zf f32 (4352B)
    __shared__ __align__(16) char ldsbuf[37120];
    short* h1s0 = (short*)(ldsbuf + 0);
    short* h1s1 = (short*)(ldsbuf + 4096);
    short* h1s2 = (short*)(ldsbuf + 8192);
    short* v1   = (short*)(ldsbuf + 12288);
    short* h2s0 = (short*)(ldsbuf + 16384);
    short* h2s1 = (short*)(ldsbuf + 18432);
    short* h2s2 = (short*)(ldsbuf + 20480);
    short* v2   = (short*)(ldsbuf + 22528);
    short* th   = (short*)(ldsbuf + 0);      // [16][704] swizzled, 22528B
    short* g1s0 = (short*)(ldsbuf + 0);
    short* g1s1 = (short*)(ldsbuf + 2048);
    short* g1s2 = (short*)(ldsbuf + 4096);
    short* u1   = (short*)(ldsbuf + 6144);
    short* g2s0 = (short*)(ldsbuf + 8192);
    short* g2s1 = (short*)(ldsbuf + 12288);
    short* g2s2 = (short*)(ldsbuf + 16384);
    short* u2   = (short*)(ldsbuf + 20480);
    short* zb0  = (short*)(ldsbuf + 24576);
    short* zb1  = (short*)(ldsbuf + 26624);
    short* zb2  = (short*)(ldsbuf + 28672);
    short* dzsb = (short*)(ldsbuf + 30720);
    float* zf   = (float*)(ldsbuf + 32768);  // [16][68]

    const int tid = threadIdx.x, lane = tid & 63, wave = tid >> 6;
    const int row0 = blockIdx.x * 16;

    // ---------------- encoder L1 (K=512, N=128): frag loads, no LDS, no barriers ----
    {
        f32x4 P[2] = {}, Q[2] = {}, V[2] = {};
        const short* bx = (const short*)(xh + (size_t)blockIdx.x * 8192);
        const short* bd = (const short*)(dxh + (size_t)blockIdx.x * 8192);
        #pragma unroll
        for (int ks = 0; ks < 16; ++ks) {
            int off = (ks * 64 + lane) * 8;
            bf16x8 f0 = *(const bf16x8*)(bx + off);
            bf16x8 f1 = *(const bf16x8*)(bx + 8192 + off);
            bf16x8 f2 = *(const bf16x8*)(bd + off);
            bf16x8 fv = *(const bf16x8*)(bd + 8192 + off);
            #pragma unroll
            for (int nf = 0; nf < 2; ++nf) {
                int blk = (wave * 2 + nf) * 16 + ks;
                bf16x8 b0 = ld_bp(Wp1, blk, lane);
                bf16x8 b1 = ld_bp(Wp1 + WSZ1, blk, lane);
                bf16x8 b2 = ld_bp(Wp1 + 2 * WSZ1, blk, lane);
                mf9(f0, f1, f2, fv, b0, b1, b2, P[nf], Q[nf], V[nf]);
            }
        }
        #pragma unroll
        for (int nf = 0; nf < 2; ++nf) {
            int col = wave * 32 + nf * 16 + (lane & 15);
            epi_store(h1s0, h1s1, h1s2, v1, 128, lane, col, P[nf], Q[nf], V[nf], be1[col]);
        }
    }
    __syncthreads();

    // ---------------- encoder L2 (K=128, N=64) ----------------
    {
        f32x4 P[1] = {}, Q[1] = {}, V[1] = {};
        layerP<4, 1>(h1s0, h1s1, h1s2, v1, 128, Wp2, WSZ2, wave, lane, P, Q, V);
        int col = wave * 16 + (lane & 15);
        epi_store(h2s0, h2s1, h2s2, v2, 64, lane, col, P[0], Q[0], V[0], be2[col]);
    }
    __syncthreads();

    // ---------------- encoder L3 (K=64, N=64) -> z, dz, zf, zb ----------------
    {
        f32x4 P[1] = {}, Q[1] = {}, V[1] = {};
        layerP<2, 1>(h2s0, h2s1, h2s2, v2, 64, Wp3, WSZ3, wave, lane, P, Q, V);
        int col = wave * 16 + (lane & 15);
        float bb = be3[col];
        #pragma unroll
        for (int q = 0; q < 4; ++q) {
            int row = (lane >> 4) * 4 + q;
            float pre = P[0][q] + Q[0][q] + bb;
            float hz = fmaxf(pre, 0.f);
            float vz = pre > 0.f ? V[0][q] : 0.f;
            zf[row * 68 + col] = hz;
            short s0, s1, s2;
            split3f(hz, s0, s1, s2);
            st_b16(zb0, 64, row, col, s0);
            st_b16(zb1, 64, row, col, s1);
            st_b16(zb2, 64, row, col, s2);
            zo[(size_t)(row0 + row) * DDIM + col] = hz;
            dz[(size_t)(row0 + row) * DDIM + col] = vz;
        }
        if (tid < 32) { int r = tid & 15; zf[r * 68 + 64 + (tid >> 4)] = (tid >> 4) ? 0.f : 1.f; }
    }
    __syncthreads();   // zf/zb ready; h1/h2 dead -> th may overwrite region A

    // ---------------- SINDy: dzs = theta(z_f32) @ xi, 3 chunks of 704 ----------------
    f32x4 sa0 = {}, sa1 = {};
    const int tr = tid & 15, tf44 = (tid >> 4) * 44;
    #pragma unroll
    for (int ch = 0; ch < 3; ++ch) {
        // build theta chunk [16][704]
        #pragma unroll
        for (int g = 0; g < 11; ++g) {
            int fl = tf44 + g * 4;
            int fg = ch * CHUNK + fl;
            int4 qa = *(const int4*)&pk[fg];
            int4 qb = *(const int4*)&pk[fg + 2];
            float t0 = zf[tr * 68 + qa.x] * zf[tr * 68 + qa.y];
            float t1 = zf[tr * 68 + qa.z] * zf[tr * 68 + qa.w];
            float t2 = zf[tr * 68 + qb.x] * zf[tr * 68 + qb.y];
            float t3 = zf[tr * 68 + qb.z] * zf[tr * 68 + qb.w];
            short arr[4] = { f2b(t0), f2b(t1), f2b(t2), f2b(t3) };
            st_b64(th, 704, tr, fl, pk4(arr));
        }
        __syncthreads();   // th visible
        #pragma unroll
        for (int kk = 0; kk < KS_PER_CHUNK; ++kk) {
            bf16x8 a = ld_af(th, 704, lane, kk * 32);
            bf16x8 b = ld_bp(xiP, wave * 66 + ch * KS_PER_CHUNK + kk, lane);
            if (kk & 1) sa1 = MFMA(a, b, sa1);
            else        sa0 = MFMA(a, b, sa0);
        }
        __syncthreads();   // th consumable for next build
    }
    {
        f32x4 sacc = sa0 + sa1;
        int col = wave * 16 + (lane & 15);
        #pragma unroll
        for (int q = 0; q < 4; ++q) {
            int row = (lane >> 4) * 4 + q;
            float v = sacc[q];
            dzs[(size_t)(row0 + row) * DDIM + col] = v;
            st_b16(dzsb, 64, row, col, f2b(v));
        }
    }
    __syncthreads();   // dzsb ready; th dead -> g1 may overwrite

    // ---------------- decoder L1 (K=64, N=64) ----------------
    {
        f32x4 P[1] = {}, Q[1] = {}, V[1] = {};
        layerP<2, 1>(zb0, zb1, zb2, dzsb, 64, Wp4, WSZ4, wave, lane, P, Q, V);
        int col = wave * 16 + (lane & 15);
        epi_store(g1s0, g1s1, g1s2, u1, 64, lane, col, P[0], Q[0], V[0], bd1[col]);
    }
    __syncthreads();

    // ---------------- decoder L2 (K=64, N=128) ----------------
    {
        f32x4 P[2] = {}, Q[2] = {}, V[2] = {};
        layerP<2, 2>(g1s0, g1s1, g1s2, u1, 64, Wp5, WSZ5, wave * 2, lane, P, Q, V);
        #pragma unroll
        for (int nf = 0; nf < 2; ++nf) {
            int col = wave * 32 + nf * 16 + (lane & 15);
            epi_store(g2s0, g2s1, g2s2, u2, 128, lane, col, P[nf], Q[nf], V[nf], bd2[col]);
        }
    }
    __syncthreads();

    // ---------------- decoder L3 (K=128, N=512) -> xh, dxh ----------------
    #pragma unroll
    for (int h = 0; h < 2; ++h) {
        f32x4 P[4] = {}, Q[4] = {}, V[4] = {};
        layerP<4, 4>(g2s0, g2s1, g2s2, u2, 128, Wp6, WSZ6, wave * 8 + h * 4, lane, P, Q, V);
        #pragma unroll
        for (int nf = 0; nf < 4; ++nf) {
            int col = wave * 128 + h * 64 + nf * 16 + (lane & 15);
            float bb = bd3[col];
            #pragma unroll
            for (int q = 0; q < 4; ++q) {
                int row = (lane >> 4) * 4 + q;
                float pre = P[nf][q] + Q[nf][q] + bb;
                xh[(size_t)(row0 + row) * IN_DIM + col] = fmaxf(pre, 0.f);
                dxh[(size_t)(row0 + row) * IN_DIM + col] = pre > 0.f ? V[nf][q] : 0.f;
            }
        }
    }
}

// =====================================================================
extern "C" void kernel_launch(void* const* d_in, const int* in_sizes, int n_in,
                              void* d_out, int out_size, void* d_ws, size_t ws_size,
                              hipStream_t stream)
{
    const float* x    = (const float*)d_in[0];
    const float* xdot = (const float*)d_in[1];
    const float* We1  = (const float*)d_in[2];
    const float* be1  = (const float*)d_in[3];
    const float* We2  = (const float*)d_in[4];
    const float* be2  = (const float*)d_in[5];
    const float* We3  = (const float*)d_in[6];
    const float* be3  = (const float*)d_in[7];
    const float* Wd1  = (const float*)d_in[8];
    const float* bd1  = (const float*)d_in[9];
    const float* Wd2  = (const float*)d_in[10];
    const float* bd2  = (const float*)d_in[11];
    const float* Wd3  = (const float*)d_in[12];
    const float* bd3  = (const float*)d_in[13];
    const float* XI   = (const float*)d_in[14];
    const float* XIm  = (const float*)d_in[15];

    float* out = (float*)d_out;
    float* xh  = out;
    float* dxh = out + (size_t)BATCH * IN_DIM;
    float* zo  = dxh + (size_t)BATCH * IN_DIM;
    float* dz  = zo + (size_t)BATCH * DDIM;
    float* dzs = dz + (size_t)BATCH * DDIM;

    // ws: pk + packed 3-plane weights + packed xi  (~1.2 MB)
    int2*  pk  = (int2*)d_ws;                      // [2112]
    short* Wp1 = (short*)(pk + NFPAD);
    short* Wp2 = Wp1 + 3 * WSZ1;
    short* Wp3 = Wp2 + 3 * WSZ2;
    short* Wp4 = Wp3 + 3 * WSZ3;
    short* Wp5 = Wp4 + 3 * WSZ4;
    short* Wp6 = Wp5 + 3 * WSZ5;
    short* xiP = Wp6 + 3 * WSZ6;                   // 4*66*64*8 shorts

    initk<<<1024, 256, 0, stream>>>(x, xdot, We1, We2, We3, Wd1, Wd2, Wd3, XI, XIm,
                                    xh, dxh, Wp1, Wp2, Wp3, Wp4, Wp5, Wp6, xiP, pk);
    fused<<<BATCH / 16, 256, 0, stream>>>(be1, be2, be3, bd1, bd2, bd3,
                                          Wp1, Wp2, Wp3, Wp4, Wp5, Wp6, xiP, pk,
                                          xh, dxh, zo, dz, dzs);
}

// Round 6
// 51.309 us; speedup vs baseline: 2.3856x; 1.3834x over previous
//
#include <hip/hip_runtime.h>

#define BATCH 4096
#define IN_DIM 512
#define H1DIM 128
#define H2DIM 64
#define DDIM 64
#define NFUNC 2081
#define NFPAD 2112
#define CHUNK 704           // 2112 = 3 * 704
#define KS_PER_CHUNK 22     // 704/32

typedef short bf16x8 __attribute__((ext_vector_type(8)));
typedef float f32x4 __attribute__((ext_vector_type(4)));
#define MFMA(a,b,c) __builtin_amdgcn_mfma_f32_16x16x32_bf16(a,b,c,0,0,0)

#define WSZ1 (H1DIM*IN_DIM)
#define WSZ2 (H2DIM*H1DIM)
#define WSZ3 (DDIM*H2DIM)
#define WSZ4 (H2DIM*DDIM)
#define WSZ5 (H1DIM*H2DIM)
#define WSZ6 (IN_DIM*H1DIM)

__device__ __forceinline__ short f2b(float f) {
    union { float f; unsigned u; } x; x.f = f;
    unsigned r = x.u + 0x7fffu + ((x.u >> 16) & 1u);
    return (short)(r >> 16);
}
__device__ __forceinline__ float b2f(short s) {
    union { unsigned u; float f; } x; x.u = ((unsigned)(unsigned short)s) << 16;
    return x.f;
}
__device__ __forceinline__ void split3f(float v, short& s0, short& s1, short& s2) {
    s0 = f2b(v); float r = v - b2f(s0);
    s1 = f2b(r); float r2 = r - b2f(s1);
    s2 = f2b(r2);
}
__device__ __forceinline__ uint2 pk4(const short* s) {
    union { short s[4]; uint2 u; } z;
    z.s[0] = s[0]; z.s[1] = s[1]; z.s[2] = s[2]; z.s[3] = s[3];
    return z.u;
}

// ---- swizzled LDS tile helpers (row stride RS shorts, byte ^= (r&7)<<4) ----
__device__ __forceinline__ void st_b16(short* t, int RS, int r, int c, short v) {
    int b = (c * 2) ^ ((r & 7) << 4);
    *(short*)((char*)(t + r * RS) + b) = v;
}
__device__ __forceinline__ void st_b64(short* t, int RS, int r, int c0, uint2 v) {
    int b = (c0 * 2) ^ ((r & 7) << 4);
    *(uint2*)((char*)(t + r * RS) + b) = v;
}
__device__ __forceinline__ bf16x8 ld_af(const short* t, int RS, int lane, int kbase) {
    int r = lane & 15;
    int b = ((kbase + (lane >> 4) * 8) * 2) ^ ((r & 7) << 4);
    return *(const bf16x8*)((const char*)(t + r * RS) + b);
}
// packed-frag global load: frag blk = contiguous 64 lanes x 16B (coalesced)
__device__ __forceinline__ bf16x8 ld_bp(const short* P, int blk, int lane) {
    return *(const bf16x8*)(P + ((size_t)blk * 64 + lane) * 8);
}

// 9-MFMA split-precision dual step
__device__ __forceinline__ void mf9(bf16x8 f0, bf16x8 f1, bf16x8 f2, bf16x8 fv,
                                    bf16x8 b0, bf16x8 b1, bf16x8 b2,
                                    f32x4& P, f32x4& Q, f32x4& V) {
    P = MFMA(f0, b0, P); Q = MFMA(f1, b1, Q);
    P = MFMA(f1, b0, P); Q = MFMA(f0, b1, Q);
    P = MFMA(f2, b0, P); Q = MFMA(f2, b1, Q);
    P = MFMA(f0, b2, P); Q = MFMA(f1, b2, Q);
    V = MFMA(fv, b0, V);
}

__device__ __forceinline__ void epi_store(short* t0, short* t1, short* t2, short* tv, int RS,
                                          int lane, int col, const f32x4& P, const f32x4& Q,
                                          const f32x4& V, float bb)
{
    #pragma unroll
    for (int q = 0; q < 4; ++q) {
        int row = (lane >> 4) * 4 + q;
        float pre = P[q] + Q[q] + bb;
        float h = fmaxf(pre, 0.f);
        short s0, s1, s2;
        split3f(h, s0, s1, s2);
        st_b16(t0, RS, row, col, s0);
        st_b16(t1, RS, row, col, s1);
        st_b16(t2, RS, row, col, s2);
        st_b16(tv, RS, row, col, pre > 0.f ? f2b(V[q]) : (short)0);
    }
}

// =====================================================================
template<int K>
__device__ void pack_w(const float* __restrict__ W, short* __restrict__ dst, int NK,
                       int gid, int nthr)
{
    for (int i = gid; i < NK; i += nthr) {
        int c = i / K, k = i % K;
        int cb = c >> 4, ks = k >> 5;
        int L = (((k >> 3) & 3) << 4) | (c & 15);
        int j = k & 7;
        int idx = ((cb * (K / 32) + ks) * 64 + L) * 8 + j;
        short s0, s1, s2; split3f(W[i], s0, s1, s2);
        dst[idx] = s0; dst[idx + NK] = s1; dst[idx + 2 * NK] = s2;
    }
}

__global__ void initk(const float* __restrict__ x, const float* __restrict__ xdot,
                      const float* __restrict__ We1, const float* __restrict__ We2,
                      const float* __restrict__ We3, const float* __restrict__ Wd1,
                      const float* __restrict__ Wd2, const float* __restrict__ Wd3,
                      const float* __restrict__ XI, const float* __restrict__ XIm,
                      float* __restrict__ xh, float* __restrict__ dxh,
                      short* Wp1, short* Wp2, short* Wp3, short* Wp4, short* Wp5, short* Wp6,
                      short* xiP, int2* pk)
{
    int gid = blockIdx.x * blockDim.x + threadIdx.x;
    int nthr = gridDim.x * blockDim.x;

    for (int i = gid; i < (BATCH / 16) * 16 * 64; i += nthr) {
        int L = i & 63, ks = (i >> 6) & 15, rb = i >> 10;
        int row = rb * 16 + (L & 15);
        int k0 = ks * 32 + ((L >> 4) << 3);
        const float* px = &x[(size_t)row * IN_DIM + k0];
        const float* pd = &xdot[(size_t)row * IN_DIM + k0];
        union { short s[8]; bf16x8 v; } a0, a1, a2, dv;
        #pragma unroll
        for (int j = 0; j < 8; ++j) {
            split3f(px[j], a0.s[j], a1.s[j], a2.s[j]);
            dv.s[j] = f2b(pd[j]);
        }
        short* bx = (short*)(xh + (size_t)rb * 8192);
        short* bd = (short*)(dxh + (size_t)rb * 8192);
        int off = (ks * 64 + L) * 8;
        *(bf16x8*)(bx + off) = a0.v;
        *(bf16x8*)(bx + 8192 + off) = a1.v;
        *(bf16x8*)(bd + off) = a2.v;
        *(bf16x8*)(bd + 8192 + off) = dv.v;
    }

    pack_w<512>(We1, Wp1, WSZ1, gid, nthr);
    pack_w<128>(We2, Wp2, WSZ2, gid, nthr);
    pack_w<64>(We3, Wp3, WSZ3, gid, nthr);
    pack_w<64>(Wd1, Wp4, WSZ4, gid, nthr);
    pack_w<64>(Wd2, Wp5, WSZ5, gid, nthr);
    pack_w<128>(Wd3, Wp6, WSZ6, gid, nthr);

    for (int i = gid; i < 4 * 66 * 64; i += nthr) {
        int cb = i / (66 * 64);
        int r = i - cb * (66 * 64);
        int ks = r >> 6, L = r & 63;
        int col = cb * 16 + (L & 15);
        union { short s[8]; bf16x8 v; } w;
        #pragma unroll
        for (int j = 0; j < 8; ++j) {
            int f = ks * 32 + ((L >> 4) << 3) + j;
            float v = (f < NFUNC) ? XI[(size_t)f * DDIM + col] * XIm[(size_t)f * DDIM + col] : 0.f;
            w.s[j] = f2b(v);
        }
        *(bf16x8*)(xiP + (size_t)i * 8) = w.v;
    }

    for (int f = gid; f < NFPAD; f += nthr) {
        int a, b;
        if (f == 0) { a = 64; b = 64; }
        else if (f <= DDIM) { a = f - 1; b = 64; }
        else if (f < NFUNC) {
            int p = f - 1 - DDIM; int i2 = 0, cum = 0;
            while (cum + (63 - i2) <= p) { cum += 63 - i2; ++i2; }
            a = i2; b = i2 + 1 + (p - cum);
        } else { a = 65; b = 65; }
        pk[f] = make_int2(a, b);
    }
}

// =====================================================================
__global__ __launch_bounds__(256, 1)
void fused(const float* __restrict__ be1, const float* __restrict__ be2,
           const float* __restrict__ be3, const float* __restrict__ bd1,
           const float* __restrict__ bd2, const float* __restrict__ bd3,
           const short* __restrict__ Wp1, const short* __restrict__ Wp2,
           const short* __restrict__ Wp3, const short* __restrict__ Wp4,
           const short* __restrict__ Wp5, const short* __restrict__ Wp6,
           const short* __restrict__ xiP, const int2* __restrict__ pk,
           float* __restrict__ xh, float* __restrict__ dxh, float* __restrict__ zo,
           float* __restrict__ dz, float* __restrict__ dzs)
{
    __shared__ __align__(16) char ldsbuf[37120];
    short* h1s0 = (short*)(ldsbuf + 0);
    short* h1s1 = (short*)(ldsbuf + 4096);
    short* h1s2 = (short*)(ldsbuf + 8192);
    short* v1   = (short*)(ldsbuf + 12288);
    short* h2s0 = (short*)(ldsbuf + 16384);
    short* h2s1 = (short*)(ldsbuf + 18432);
    short* h2s2 = (short*)(ldsbuf + 20480);
    short* v2   = (short*)(ldsbuf + 22528);
    short* th   = (short*)(ldsbuf + 0);      // [16][704] swizzled
    short* g1s0 = (short*)(ldsbuf + 0);
    short* g1s1 = (short*)(ldsbuf + 2048);
    short* g1s2 = (short*)(ldsbuf + 4096);
    short* u1   = (short*)(ldsbuf + 6144);
    short* g2s0 = (short*)(ldsbuf + 8192);
    short* g2s1 = (short*)(ldsbuf + 12288);
    short* g2s2 = (short*)(ldsbuf + 16384);
    short* u2   = (short*)(ldsbuf + 20480);
    short* zb0  = (short*)(ldsbuf + 24576);
    short* zb1  = (short*)(ldsbuf + 26624);
    short* zb2  = (short*)(ldsbuf + 28672);
    short* dzsb = (short*)(ldsbuf + 30720);
    float* zf   = (float*)(ldsbuf + 32768);  // [16][68]

    const int tid = threadIdx.x, lane = tid & 63, wave = tid >> 6;
    const int row0 = blockIdx.x * 16;
    const int c16 = lane & 15;

    // ---- bias preload (fully hidden under L1) ----
    float bb1[2] = { be1[wave * 32 + c16], be1[wave * 32 + 16 + c16] };
    float bb2 = be2[wave * 16 + c16];
    float bb3 = be3[wave * 16 + c16];
    float bD1 = bd1[wave * 16 + c16];
    float bD2[2] = { bd2[wave * 32 + c16], bd2[wave * 32 + 16 + c16] };
    float bD3[8];
    #pragma unroll
    for (int i = 0; i < 8; ++i) bD3[i] = bd3[wave * 128 + i * 16 + c16];

    // L2 B-prefetch lives across the L1 segment's end
    bf16x8 L2B[4][3];

    // ================= encoder L1 (K=512, N=128): depth-3 reg pipeline ========
    {
        const short* bx = (const short*)(xh + (size_t)blockIdx.x * 8192);
        const short* bd = (const short*)(dxh + (size_t)blockIdx.x * 8192);
        f32x4 P[2] = {}, Q[2] = {}, V[2] = {};
        bf16x8 A0[3], A1[3], A2[3], Ad[3];
        bf16x8 B0[3][2], B1[3][2], B2[3][2];
#define L1_LA(ks, sl) { int off = ((ks) * 64 + lane) * 8; \
        A0[sl] = *(const bf16x8*)(bx + off); A1[sl] = *(const bf16x8*)(bx + 8192 + off); \
        A2[sl] = *(const bf16x8*)(bd + off); Ad[sl] = *(const bf16x8*)(bd + 8192 + off); }
#define L1_LB(ks, sl) { int bA = (wave * 2) * 16 + (ks), bB = (wave * 2 + 1) * 16 + (ks); \
        B0[sl][0] = ld_bp(Wp1, bA, lane); B1[sl][0] = ld_bp(Wp1 + WSZ1, bA, lane); B2[sl][0] = ld_bp(Wp1 + 2 * WSZ1, bA, lane); \
        B0[sl][1] = ld_bp(Wp1, bB, lane); B1[sl][1] = ld_bp(Wp1 + WSZ1, bB, lane); B2[sl][1] = ld_bp(Wp1 + 2 * WSZ1, bB, lane); }
        L1_LA(0, 0) L1_LB(0, 0)
        L1_LA(1, 1) L1_LB(1, 1)
        L1_LA(2, 2) L1_LB(2, 2)
        #pragma unroll
        for (int ks = 0; ks < 16; ++ks) {
            const int sl = ks % 3;
            mf9(A0[sl], A1[sl], A2[sl], Ad[sl], B0[sl][0], B1[sl][0], B2[sl][0], P[0], Q[0], V[0]);
            mf9(A0[sl], A1[sl], A2[sl], Ad[sl], B0[sl][1], B1[sl][1], B2[sl][1], P[1], Q[1], V[1]);
            if (ks + 3 < 16) { L1_LA(ks + 3, sl) L1_LB(ks + 3, sl) }
        }
#undef L1_LA
#undef L1_LB
        #pragma unroll
        for (int nf = 0; nf < 2; ++nf) {
            int col = wave * 32 + nf * 16 + c16;
            epi_store(h1s0, h1s1, h1s2, v1, 128, lane, col, P[nf], Q[nf], V[nf], bb1[nf]);
        }
        // issue L2 B prefetch before the barrier (latency absorbed at sync)
        #pragma unroll
        for (int ks = 0; ks < 4; ++ks) {
            int blk = wave * 4 + ks;
            L2B[ks][0] = ld_bp(Wp2, blk, lane);
            L2B[ks][1] = ld_bp(Wp2 + WSZ2, blk, lane);
            L2B[ks][2] = ld_bp(Wp2 + 2 * WSZ2, blk, lane);
        }
    }
    __syncthreads();

    // ================= encoder L2 (K=128, N=64): all-upfront ========
    bf16x8 L3B[2][3];
    {
        bf16x8 Aa[4][4];
        #pragma unroll
        for (int ks = 0; ks < 4; ++ks) {
            Aa[ks][0] = ld_af(h1s0, 128, lane, ks * 32);
            Aa[ks][1] = ld_af(h1s1, 128, lane, ks * 32);
            Aa[ks][2] = ld_af(h1s2, 128, lane, ks * 32);
            Aa[ks][3] = ld_af(v1, 128, lane, ks * 32);
        }
        f32x4 P = {}, Q = {}, V = {};
        #pragma unroll
        for (int ks = 0; ks < 4; ++ks)
            mf9(Aa[ks][0], Aa[ks][1], Aa[ks][2], Aa[ks][3], L2B[ks][0], L2B[ks][1], L2B[ks][2], P, Q, V);
        epi_store(h2s0, h2s1, h2s2, v2, 64, lane, wave * 16 + c16, P, Q, V, bb2);
        #pragma unroll
        for (int ks = 0; ks < 2; ++ks) {
            int blk = wave * 2 + ks;
            L3B[ks][0] = ld_bp(Wp3, blk, lane);
            L3B[ks][1] = ld_bp(Wp3 + WSZ3, blk, lane);
            L3B[ks][2] = ld_bp(Wp3 + 2 * WSZ3, blk, lane);
        }
    }
    __syncthreads();

    // ================= encoder L3 (K=64, N=64) -> z, dz, zf, zb ========
    {
        bf16x8 Aa[2][4];
        #pragma unroll
        for (int ks = 0; ks < 2; ++ks) {
            Aa[ks][0] = ld_af(h2s0, 64, lane, ks * 32);
            Aa[ks][1] = ld_af(h2s1, 64, lane, ks * 32);
            Aa[ks][2] = ld_af(h2s2, 64, lane, ks * 32);
            Aa[ks][3] = ld_af(v2, 64, lane, ks * 32);
        }
        f32x4 P = {}, Q = {}, V = {};
        #pragma unroll
        for (int ks = 0; ks < 2; ++ks)
            mf9(Aa[ks][0], Aa[ks][1], Aa[ks][2], Aa[ks][3], L3B[ks][0], L3B[ks][1], L3B[ks][2], P, Q, V);
        int col = wave * 16 + c16;
        #pragma unroll
        for (int q = 0; q < 4; ++q) {
            int row = (lane >> 4) * 4 + q;
            float pre = P[q] + Q[q] + bb3;
            float hz = fmaxf(pre, 0.f);
            float vz = pre > 0.f ? V[q] : 0.f;
            zf[row * 68 + col] = hz;
            short s0, s1, s2;
            split3f(hz, s0, s1, s2);
            st_b16(zb0, 64, row, col, s0);
            st_b16(zb1, 64, row, col, s1);
            st_b16(zb2, 64, row, col, s2);
            zo[(size_t)(row0 + row) * DDIM + col] = hz;
            dz[(size_t)(row0 + row) * DDIM + col] = vz;
        }
        if (tid < 32) { int r = tid & 15; zf[r * 68 + 64 + (tid >> 4)] = (tid >> 4) ? 0.f : 1.f; }
    }
    __syncthreads();   // zf/zb ready; h1/h2 dead -> th may overwrite

    // ================= SINDy: 3 chunks of 704, whole-chunk xi preload ========
    {
        f32x4 sa0 = {}, sa1 = {};
        const int tr = tid & 15, tf44 = (tid >> 4) * 44;
        bf16x8 X[KS_PER_CHUNK];
        #pragma unroll
        for (int kk = 0; kk < KS_PER_CHUNK; ++kk)
            X[kk] = ld_bp(xiP, wave * 66 + kk, lane);
        #pragma unroll
        for (int ch = 0; ch < 3; ++ch) {
            #pragma unroll
            for (int g = 0; g < 11; ++g) {
                int fl = tf44 + g * 4;
                int fg = ch * CHUNK + fl;
                int4 qa = *(const int4*)&pk[fg];
                int4 qb = *(const int4*)&pk[fg + 2];
                float t0 = zf[tr * 68 + qa.x] * zf[tr * 68 + qa.y];
                float t1 = zf[tr * 68 + qa.z] * zf[tr * 68 + qa.w];
                float t2 = zf[tr * 68 + qb.x] * zf[tr * 68 + qb.y];
                float t3 = zf[tr * 68 + qb.z] * zf[tr * 68 + qb.w];
                short arr[4] = { f2b(t0), f2b(t1), f2b(t2), f2b(t3) };
                st_b64(th, 704, tr, fl, pk4(arr));
            }
            __syncthreads();   // th visible
            #pragma unroll
            for (int kk = 0; kk < KS_PER_CHUNK; ++kk) {
                bf16x8 a = ld_af(th, 704, lane, kk * 32);
                if (kk & 1) sa1 = MFMA(a, X[kk], sa1);
                else        sa0 = MFMA(a, X[kk], sa0);
            }
            if (ch < 2) {
                #pragma unroll
                for (int kk = 0; kk < KS_PER_CHUNK; ++kk)
                    X[kk] = ld_bp(xiP, wave * 66 + (ch + 1) * KS_PER_CHUNK + kk, lane);
            }
            __syncthreads();   // th reusable
        }
        f32x4 sacc = sa0 + sa1;
        int col = wave * 16 + c16;
        #pragma unroll
        for (int q = 0; q < 4; ++q) {
            int row = (lane >> 4) * 4 + q;
            float v = sacc[q];
            dzs[(size_t)(row0 + row) * DDIM + col] = v;
            st_b16(dzsb, 64, row, col, f2b(v));
        }
    }
    // prefetch dec1 B before barrier
    bf16x8 D1B[2][3];
    #pragma unroll
    for (int ks = 0; ks < 2; ++ks) {
        int blk = wave * 2 + ks;
        D1B[ks][0] = ld_bp(Wp4, blk, lane);
        D1B[ks][1] = ld_bp(Wp4 + WSZ4, blk, lane);
        D1B[ks][2] = ld_bp(Wp4 + 2 * WSZ4, blk, lane);
    }
    __syncthreads();   // dzsb ready; th dead -> g1 may overwrite

    // ================= decoder L1 (K=64, N=64) ========
    bf16x8 D2B[2][2][3];   // [cf][ks][plane]
    {
        bf16x8 Aa[2][4];
        #pragma unroll
        for (int ks = 0; ks < 2; ++ks) {
            Aa[ks][0] = ld_af(zb0, 64, lane, ks * 32);
            Aa[ks][1] = ld_af(zb1, 64, lane, ks * 32);
            Aa[ks][2] = ld_af(zb2, 64, lane, ks * 32);
            Aa[ks][3] = ld_af(dzsb, 64, lane, ks * 32);
        }
        f32x4 P = {}, Q = {}, V = {};
        #pragma unroll
        for (int ks = 0; ks < 2; ++ks)
            mf9(Aa[ks][0], Aa[ks][1], Aa[ks][2], Aa[ks][3], D1B[ks][0], D1B[ks][1], D1B[ks][2], P, Q, V);
        epi_store(g1s0, g1s1, g1s2, u1, 64, lane, wave * 16 + c16, P, Q, V, bD1);
        #pragma unroll
        for (int cf = 0; cf < 2; ++cf)
            #pragma unroll
            for (int ks = 0; ks < 2; ++ks) {
                int blk = (wave * 2 + cf) * 2 + ks;
                D2B[cf][ks][0] = ld_bp(Wp5, blk, lane);
                D2B[cf][ks][1] = ld_bp(Wp5 + WSZ5, blk, lane);
                D2B[cf][ks][2] = ld_bp(Wp5 + 2 * WSZ5, blk, lane);
            }
    }
    __syncthreads();

    // ================= decoder L2 (K=64, N=128) ========
    {
        bf16x8 Aa[2][4];
        #pragma unroll
        for (int ks = 0; ks < 2; ++ks) {
            Aa[ks][0] = ld_af(g1s0, 64, lane, ks * 32);
            Aa[ks][1] = ld_af(g1s1, 64, lane, ks * 32);
            Aa[ks][2] = ld_af(g1s2, 64, lane, ks * 32);
            Aa[ks][3] = ld_af(u1, 64, lane, ks * 32);
        }
        f32x4 P[2] = {}, Q[2] = {}, V[2] = {};
        #pragma unroll
        for (int cf = 0; cf < 2; ++cf)
            #pragma unroll
            for (int ks = 0; ks < 2; ++ks)
                mf9(Aa[ks][0], Aa[ks][1], Aa[ks][2], Aa[ks][3],
                    D2B[cf][ks][0], D2B[cf][ks][1], D2B[cf][ks][2], P[cf], Q[cf], V[cf]);
        #pragma unroll
        for (int cf = 0; cf < 2; ++cf) {
            int col = wave * 32 + cf * 16 + c16;
            epi_store(g2s0, g2s1, g2s2, u2, 128, lane, col, P[cf], Q[cf], V[cf], bD2[cf]);
        }
    }
    __syncthreads();

    // ================= decoder L3 (K=128, N=512): depth-4 B pipeline ========
    #pragma unroll
    for (int h = 0; h < 2; ++h) {
        f32x4 P[4] = {}, Q[4] = {}, V[4] = {};
        bf16x8 Bp[4][3];
        bf16x8 Ax0[2], Ax1[2], Ax2[2], Axv[2];
#define D3_LA(ks, b) { Ax0[b] = ld_af(g2s0, 128, lane, (ks) * 32); Ax1[b] = ld_af(g2s1, 128, lane, (ks) * 32); \
                       Ax2[b] = ld_af(g2s2, 128, lane, (ks) * 32); Axv[b] = ld_af(u2, 128, lane, (ks) * 32); }
#define D3_LB(s, sl) { int blk = (wave * 8 + h * 4 + ((s) & 3)) * 4 + ((s) >> 2); \
        Bp[sl][0] = ld_bp(Wp6, blk, lane); Bp[sl][1] = ld_bp(Wp6 + WSZ6, blk, lane); Bp[sl][2] = ld_bp(Wp6 + 2 * WSZ6, blk, lane); }
        D3_LA(0, 0)
        D3_LB(0, 0) D3_LB(1, 1) D3_LB(2, 2) D3_LB(3, 3)
        #pragma unroll
        for (int ks = 0; ks < 4; ++ks) {
            if (ks < 3) D3_LA(ks + 1, (ks + 1) & 1)
            #pragma unroll
            for (int cf = 0; cf < 4; ++cf) {
                const int s = ks * 4 + cf, sl = s & 3;
                mf9(Ax0[ks & 1], Ax1[ks & 1], Ax2[ks & 1], Axv[ks & 1],
                    Bp[sl][0], Bp[sl][1], Bp[sl][2], P[cf], Q[cf], V[cf]);
                if (s + 4 < 16) D3_LB(s + 4, sl)
            }
        }
#undef D3_LA
#undef D3_LB
        #pragma unroll
        for (int cf = 0; cf < 4; ++cf) {
            int col = wave * 128 + h * 64 + cf * 16 + c16;
            float bb = bD3[h * 4 + cf];
            #pragma unroll
            for (int q = 0; q < 4; ++q) {
                int row = (lane >> 4) * 4 + q;
                float pre = P[cf][q] + Q[cf][q] + bb;
                xh[(size_t)(row0 + row) * IN_DIM + col] = fmaxf(pre, 0.f);
                dxh[(size_t)(row0 + row) * IN_DIM + col] = pre > 0.f ? V[cf][q] : 0.f;
            }
        }
    }
}

// =====================================================================
extern "C" void kernel_launch(void* const* d_in, const int* in_sizes, int n_in,
                              void* d_out, int out_size, void* d_ws, size_t ws_size,
                              hipStream_t stream)
{
    const float* x    = (const float*)d_in[0];
    const float* xdot = (const float*)d_in[1];
    const float* We1  = (const float*)d_in[2];
    const float* be1  = (const float*)d_in[3];
    const float* We2  = (const float*)d_in[4];
    const float* be2  = (const float*)d_in[5];
    const float* We3  = (const float*)d_in[6];
    const float* be3  = (const float*)d_in[7];
    const float* Wd1  = (const float*)d_in[8];
    const float* bd1  = (const float*)d_in[9];
    const float* Wd2  = (const float*)d_in[10];
    const float* bd2  = (const float*)d_in[11];
    const float* Wd3  = (const float*)d_in[12];
    const float* bd3  = (const float*)d_in[13];
    const float* XI   = (const float*)d_in[14];
    const float* XIm  = (const float*)d_in[15];

    float* out = (float*)d_out;
    float* xh  = out;
    float* dxh = out + (size_t)BATCH * IN_DIM;
    float* zo  = dxh + (size_t)BATCH * IN_DIM;
    float* dz  = zo + (size_t)BATCH * DDIM;
    float* dzs = dz + (size_t)BATCH * DDIM;

    int2*  pk  = (int2*)d_ws;
    short* Wp1 = (short*)(pk + NFPAD);
    short* Wp2 = Wp1 + 3 * WSZ1;
    short* Wp3 = Wp2 + 3 * WSZ2;
    short* Wp4 = Wp3 + 3 * WSZ3;
    short* Wp5 = Wp4 + 3 * WSZ4;
    short* Wp6 = Wp5 + 3 * WSZ5;
    short* xiP = Wp6 + 3 * WSZ6;

    initk<<<1024, 256, 0, stream>>>(x, xdot, We1, We2, We3, Wd1, Wd2, Wd3, XI, XIm,
                                    xh, dxh, Wp1, Wp2, Wp3, Wp4, Wp5, Wp6, xiP, pk);
    fused<<<BATCH / 16, 256, 0, stream>>>(be1, be2, be3, bd1, bd2, bd3,
                                          Wp1, Wp2, Wp3, Wp4, Wp5, Wp6, xiP, pk,
                                          xh, dxh, zo, dz, dzs);
}

// Round 8
// 48.647 us; speedup vs baseline: 2.5161x; 1.0547x over previous
//
#include <hip/hip_runtime.h>

#define BATCH 4096
#define IN_DIM 512
#define H1DIM 128
#define H2DIM 64
#define DDIM 64
#define NFUNC 2081
#define NFPAD 2112
#define CHUNK 704           // 2112 = 3 * 704
#define KS_PER_CHUNK 22     // 704/32

typedef short bf16x8 __attribute__((ext_vector_type(8)));
typedef float f32x4 __attribute__((ext_vector_type(4)));
#define MFMA(a,b,c) __builtin_amdgcn_mfma_f32_16x16x32_bf16(a,b,c,0,0,0)

#define WSZ1 (H1DIM*IN_DIM)
#define WSZ2 (H2DIM*H1DIM)
#define WSZ3 (DDIM*H2DIM)
#define WSZ4 (H2DIM*DDIM)
#define WSZ5 (H1DIM*H2DIM)
#define WSZ6 (IN_DIM*H1DIM)

__device__ __forceinline__ short f2b(float f) {
    union { float f; unsigned u; } x; x.f = f;
    unsigned r = x.u + 0x7fffu + ((x.u >> 16) & 1u);
    return (short)(r >> 16);
}
__device__ __forceinline__ float b2f(short s) {
    union { unsigned u; float f; } x; x.u = ((unsigned)(unsigned short)s) << 16;
    return x.f;
}
__device__ __forceinline__ void split3f(float v, short& s0, short& s1, short& s2) {
    s0 = f2b(v); float r = v - b2f(s0);
    s1 = f2b(r); float r2 = r - b2f(s1);
    s2 = f2b(r2);
}
__device__ __forceinline__ uint2 pk4(const short* s) {
    union { short s[4]; uint2 u; } z;
    z.s[0] = s[0]; z.s[1] = s[1]; z.s[2] = s[2]; z.s[3] = s[3];
    return z.u;
}

// counted wait on our own DMA queue; memory clobber + sched fence pins order
template<int N> __device__ __forceinline__ void waitv() {
    asm volatile("s_waitcnt vmcnt(%0)" :: "n"(N) : "memory");
    __builtin_amdgcn_sched_barrier(0);
}

// ---- swizzled LDS tile helpers (row stride RS shorts, byte ^= (r&7)<<4) ----
__device__ __forceinline__ void st_b16(short* t, int RS, int r, int c, short v) {
    int b = (c * 2) ^ ((r & 7) << 4);
    *(short*)((char*)(t + r * RS) + b) = v;
}
__device__ __forceinline__ void st_b64(short* t, int RS, int r, int c0, uint2 v) {
    int b = (c0 * 2) ^ ((r & 7) << 4);
    *(uint2*)((char*)(t + r * RS) + b) = v;
}
__device__ __forceinline__ bf16x8 ld_af(const short* t, int RS, int lane, int kbase) {
    int r = lane & 15;
    int b = ((kbase + (lane >> 4) * 8) * 2) ^ ((r & 7) << 4);
    return *(const bf16x8*)((const char*)(t + r * RS) + b);
}
// packed-frag global load (plain compiler load; used in small segments)
__device__ __forceinline__ bf16x8 ld_bp(const short* P, int blk, int lane) {
    return *(const bf16x8*)(P + ((size_t)blk * 64 + lane) * 8);
}

// 9-MFMA split-precision dual step (order identical to r6 -> same numerics)
__device__ __forceinline__ void mf9(bf16x8 f0, bf16x8 f1, bf16x8 f2, bf16x8 fv,
                                    bf16x8 b0, bf16x8 b1, bf16x8 b2,
                                    f32x4& P, f32x4& Q, f32x4& V) {
    P = MFMA(f0, b0, P); Q = MFMA(f1, b1, Q);
    P = MFMA(f1, b0, P); Q = MFMA(f0, b1, Q);
    P = MFMA(f2, b0, P); Q = MFMA(f2, b1, Q);
    P = MFMA(f0, b2, P); Q = MFMA(f1, b2, Q);
    V = MFMA(fv, b0, V);
}

__device__ __forceinline__ void epi_store(short* t0, short* t1, short* t2, short* tv, int RS,
                                          int lane, int col, const f32x4& P, const f32x4& Q,
                                          const f32x4& V, float bb)
{
    #pragma unroll
    for (int q = 0; q < 4; ++q) {
        int row = (lane >> 4) * 4 + q;
        float pre = P[q] + Q[q] + bb;
        float h = fmaxf(pre, 0.f);
        short s0, s1, s2;
        split3f(h, s0, s1, s2);
        st_b16(t0, RS, row, col, s0);
        st_b16(t1, RS, row, col, s1);
        st_b16(t2, RS, row, col, s2);
        st_b16(tv, RS, row, col, pre > 0.f ? f2b(V[q]) : (short)0);
    }
}

// =====================================================================
template<int K>
__device__ void pack_w(const float* __restrict__ W, short* __restrict__ dst, int NK,
                       int gid, int nthr)
{
    for (int i = gid; i < NK; i += nthr) {
        int c = i / K, k = i % K;
        int cb = c >> 4, ks = k >> 5;
        int L = (((k >> 3) & 3) << 4) | (c & 15);
        int j = k & 7;
        int idx = ((cb * (K / 32) + ks) * 64 + L) * 8 + j;
        short s0, s1, s2; split3f(W[i], s0, s1, s2);
        dst[idx] = s0; dst[idx + NK] = s1; dst[idx + 2 * NK] = s2;
    }
}

__global__ void initk(const float* __restrict__ x, const float* __restrict__ xdot,
                      const float* __restrict__ We1, const float* __restrict__ We2,
                      const float* __restrict__ We3, const float* __restrict__ Wd1,
                      const float* __restrict__ Wd2, const float* __restrict__ Wd3,
                      const float* __restrict__ XI, const float* __restrict__ XIm,
                      float* __restrict__ xh, float* __restrict__ dxh,
                      short* Wp1, short* Wp2, short* Wp3, short* Wp4, short* Wp5, short* Wp6,
                      short* xiP, int2* pk)
{
    int gid = blockIdx.x * blockDim.x + threadIdx.x;
    int nthr = gridDim.x * blockDim.x;

    for (int i = gid; i < (BATCH / 16) * 16 * 64; i += nthr) {
        int L = i & 63, ks = (i >> 6) & 15, rb = i >> 10;
        int row = rb * 16 + (L & 15);
        int k0 = ks * 32 + ((L >> 4) << 3);
        const float* px = &x[(size_t)row * IN_DIM + k0];
        const float* pd = &xdot[(size_t)row * IN_DIM + k0];
        union { short s[8]; bf16x8 v; } a0, a1, a2, dv;
        #pragma unroll
        for (int j = 0; j < 8; ++j) {
            split3f(px[j], a0.s[j], a1.s[j], a2.s[j]);
            dv.s[j] = f2b(pd[j]);
        }
        short* bx = (short*)(xh + (size_t)rb * 8192);
        short* bd = (short*)(dxh + (size_t)rb * 8192);
        int off = (ks * 64 + L) * 8;
        *(bf16x8*)(bx + off) = a0.v;
        *(bf16x8*)(bx + 8192 + off) = a1.v;
        *(bf16x8*)(bd + off) = a2.v;
        *(bf16x8*)(bd + 8192 + off) = dv.v;
    }

    pack_w<512>(We1, Wp1, WSZ1, gid, nthr);
    pack_w<128>(We2, Wp2, WSZ2, gid, nthr);
    pack_w<64>(We3, Wp3, WSZ3, gid, nthr);
    pack_w<64>(Wd1, Wp4, WSZ4, gid, nthr);
    pack_w<64>(Wd2, Wp5, WSZ5, gid, nthr);
    pack_w<128>(Wd3, Wp6, WSZ6, gid, nthr);

    for (int i = gid; i < 4 * 66 * 64; i += nthr) {
        int cb = i / (66 * 64);
        int r = i - cb * (66 * 64);
        int ks = r >> 6, L = r & 63;
        int col = cb * 16 + (L & 15);
        union { short s[8]; bf16x8 v; } w;
        #pragma unroll
        for (int j = 0; j < 8; ++j) {
            int f = ks * 32 + ((L >> 4) << 3) + j;
            float v = (f < NFUNC) ? XI[(size_t)f * DDIM + col] * XIm[(size_t)f * DDIM + col] : 0.f;
            w.s[j] = f2b(v);
        }
        *(bf16x8*)(xiP + (size_t)i * 8) = w.v;
    }

    for (int f = gid; f < NFPAD; f += nthr) {
        int a, b;
        if (f == 0) { a = 64; b = 64; }
        else if (f <= DDIM) { a = f - 1; b = 64; }
        else if (f < NFUNC) {
            int p = f - 1 - DDIM; int i2 = 0, cum = 0;
            while (cum + (63 - i2) <= p) { cum += 63 - i2; ++i2; }
            a = i2; b = i2 + 1 + (p - cum);
        } else { a = 65; b = 65; }
        pk[f] = make_int2(a, b);
    }
}

// =====================================================================
__global__ __launch_bounds__(256, 1)
void fused(const float* __restrict__ be1, const float* __restrict__ be2,
           const float* __restrict__ be3, const float* __restrict__ bd1,
           const float* __restrict__ bd2, const float* __restrict__ bd3,
           const short* __restrict__ Wp1, const short* __restrict__ Wp2,
           const short* __restrict__ Wp3, const short* __restrict__ Wp4,
           const short* __restrict__ Wp5, const short* __restrict__ Wp6,
           const short* __restrict__ xiP, const int2* __restrict__ pk,
           float* __restrict__ xh, float* __restrict__ dxh, float* __restrict__ zo,
           float* __restrict__ dz, float* __restrict__ dzs)
{
    // 120 KB shared. During L1: per-wave DMA pipeline slots cover [0,120K).
    // After L1 (barrier-guarded) the r6 alias map lives in [0,37120).
    // During dec3: per-wave B slots at [40960,90112) (everything there is dead).
    __shared__ __align__(1024) char lds[122880];
#define GLL(gp, lo) __builtin_amdgcn_global_load_lds( \
        (const __attribute__((address_space(1))) unsigned int*)(gp), \
        (__attribute__((address_space(3))) unsigned int*)&lds[lo], 16, 0, 0)

    short* h1s0 = (short*)(lds + 0);
    short* h1s1 = (short*)(lds + 4096);
    short* h1s2 = (short*)(lds + 8192);
    short* v1   = (short*)(lds + 12288);
    short* h2s0 = (short*)(lds + 16384);
    short* h2s1 = (short*)(lds + 18432);
    short* h2s2 = (short*)(lds + 20480);
    short* v2   = (short*)(lds + 22528);
    short* th   = (short*)(lds + 0);      // [16][704] swizzled
    short* g1s0 = (short*)(lds + 0);
    short* g1s1 = (short*)(lds + 2048);
    short* g1s2 = (short*)(lds + 4096);
    short* u1   = (short*)(lds + 6144);
    short* g2s0 = (short*)(lds + 8192);
    short* g2s1 = (short*)(lds + 12288);
    short* g2s2 = (short*)(lds + 16384);
    short* u2   = (short*)(lds + 20480);
    short* zb0  = (short*)(lds + 24576);
    short* zb1  = (short*)(lds + 26624);
    short* zb2  = (short*)(lds + 28672);
    short* dzsb = (short*)(lds + 30720);
    float* zf   = (float*)(lds + 32768);  // [16][68]

    const int tid = threadIdx.x, lane = tid & 63, wave = tid >> 6;
    const int row0 = blockIdx.x * 16;
    const int c16 = lane & 15;
    const int lane16 = lane * 16;
    const int tr = tid & 15, tf44 = (tid >> 4) * 44;

    // ---- bias preload (plain loads; extras in vmcnt queue are harmless) ----
    float bb1[2] = { be1[wave * 32 + c16], be1[wave * 32 + 16 + c16] };
    float bb2 = be2[wave * 16 + c16];
    float bb3 = be3[wave * 16 + c16];
    float bD1 = bd1[wave * 16 + c16];
    float bD2[2] = { bd2[wave * 32 + c16], bd2[wave * 32 + 16 + c16] };
    float bD3[8];
    #pragma unroll
    for (int i = 0; i < 8; ++i) bD3[i] = bd3[wave * 128 + i * 16 + c16];

    // ================= encoder L1 (K=512, N=128): global_load_lds pipeline ====
    // depth 3, 10 DMAs/step (4 A + 6 B), wave-private slots, no barriers inside.
    f32x4 P1[2] = {}, Q1[2] = {}, V1[2] = {};
    {
        const char* bxc = (const char*)(xh + (size_t)blockIdx.x * 8192);
        const char* bdc = (const char*)(dxh + (size_t)blockIdx.x * 8192);
        const char* w1ac = (const char*)Wp1;
        const char* w1bc = (const char*)(Wp1 + WSZ1);
        const char* w1cc = (const char*)(Wp1 + 2 * WSZ1);
#define SLOT1(d) (unsigned)(wave * 30720 + (d) * 10240)
#define ISS1(ks, d) { unsigned sb = SLOT1(d); \
        const char* ga = bxc + (ks) * 1024 + lane16; \
        GLL(ga, sb);            GLL(ga + 16384, sb + 1024); \
        const char* gd = bdc + (ks) * 1024 + lane16; \
        GLL(gd, sb + 2048);     GLL(gd + 16384, sb + 3072); \
        int bA = ((wave * 2) * 16 + (ks)) * 1024 + lane16; \
        int bB = ((wave * 2 + 1) * 16 + (ks)) * 1024 + lane16; \
        GLL(w1ac + bA, sb + 4096); GLL(w1bc + bA, sb + 5120); GLL(w1cc + bA, sb + 6144); \
        GLL(w1ac + bB, sb + 7168); GLL(w1bc + bB, sb + 8192); GLL(w1cc + bB, sb + 9216); }
#define STEP1(ks, WN) { waitv<WN>(); unsigned sb = SLOT1((ks) % 3); \
        bf16x8 f0  = *(const bf16x8*)&lds[sb + lane16]; \
        bf16x8 f1  = *(const bf16x8*)&lds[sb + 1024 + lane16]; \
        bf16x8 f2  = *(const bf16x8*)&lds[sb + 2048 + lane16]; \
        bf16x8 fv  = *(const bf16x8*)&lds[sb + 3072 + lane16]; \
        bf16x8 b00 = *(const bf16x8*)&lds[sb + 4096 + lane16]; \
        bf16x8 b01 = *(const bf16x8*)&lds[sb + 5120 + lane16]; \
        bf16x8 b02 = *(const bf16x8*)&lds[sb + 6144 + lane16]; \
        bf16x8 b10 = *(const bf16x8*)&lds[sb + 7168 + lane16]; \
        bf16x8 b11 = *(const bf16x8*)&lds[sb + 8192 + lane16]; \
        bf16x8 b12 = *(const bf16x8*)&lds[sb + 9216 + lane16]; \
        mf9(f0, f1, f2, fv, b00, b01, b02, P1[0], Q1[0], V1[0]); \
        mf9(f0, f1, f2, fv, b10, b11, b12, P1[1], Q1[1], V1[1]); \
        __builtin_amdgcn_sched_barrier(0); \
        if ((ks) + 3 < 16) ISS1((ks) + 3, (ks) % 3) }

        ISS1(0, 0) ISS1(1, 1) ISS1(2, 2)
        STEP1(0, 20)  STEP1(1, 20)  STEP1(2, 20)  STEP1(3, 20)
        STEP1(4, 20)  STEP1(5, 20)  STEP1(6, 20)  STEP1(7, 20)
        STEP1(8, 20)  STEP1(9, 20)  STEP1(10, 20) STEP1(11, 20)
        STEP1(12, 20) STEP1(13, 20) STEP1(14, 10) STEP1(15, 0)
#undef ISS1
#undef STEP1
#undef SLOT1
    }
    __syncthreads();   // all waves done with pipeline slots -> alias region safe
    #pragma unroll
    for (int nf = 0; nf < 2; ++nf) {
        int col = wave * 32 + nf * 16 + c16;
        epi_store(h1s0, h1s1, h1s2, v1, 128, lane, col, P1[nf], Q1[nf], V1[nf], bb1[nf]);
    }
    // L2 B prefetch (plain loads, r6 style)
    bf16x8 L2B[4][3];
    #pragma unroll
    for (int ks = 0; ks < 4; ++ks) {
        int blk = wave * 4 + ks;
        L2B[ks][0] = ld_bp(Wp2, blk, lane);
        L2B[ks][1] = ld_bp(Wp2 + WSZ2, blk, lane);
        L2B[ks][2] = ld_bp(Wp2 + 2 * WSZ2, blk, lane);
    }
    __syncthreads();

    // ================= encoder L2 (K=128, N=64) ========
    bf16x8 L3B[2][3];
    {
        bf16x8 Aa[4][4];
        #pragma unroll
        for (int ks = 0; ks < 4; ++ks) {
            Aa[ks][0] = ld_af(h1s0, 128, lane, ks * 32);
            Aa[ks][1] = ld_af(h1s1, 128, lane, ks * 32);
            Aa[ks][2] = ld_af(h1s2, 128, lane, ks * 32);
            Aa[ks][3] = ld_af(v1, 128, lane, ks * 32);
        }
        #pragma unroll
        for (int ks = 0; ks < 2; ++ks) {
            int blk = wave * 2 + ks;
            L3B[ks][0] = ld_bp(Wp3, blk, lane);
            L3B[ks][1] = ld_bp(Wp3 + WSZ3, blk, lane);
            L3B[ks][2] = ld_bp(Wp3 + 2 * WSZ3, blk, lane);
        }
        f32x4 P = {}, Q = {}, V = {};
        #pragma unroll
        for (int ks = 0; ks < 4; ++ks)
            mf9(Aa[ks][0], Aa[ks][1], Aa[ks][2], Aa[ks][3], L2B[ks][0], L2B[ks][1], L2B[ks][2], P, Q, V);
        epi_store(h2s0, h2s1, h2s2, v2, 64, lane, wave * 16 + c16, P, Q, V, bb2);
    }
    __syncthreads();

    // ================= encoder L3 (K=64) -> z ========
    bf16x8 X[KS_PER_CHUNK];
    {
        bf16x8 Aa[2][4];
        #pragma unroll
        for (int ks = 0; ks < 2; ++ks) {
            Aa[ks][0] = ld_af(h2s0, 64, lane, ks * 32);
            Aa[ks][1] = ld_af(h2s1, 64, lane, ks * 32);
            Aa[ks][2] = ld_af(h2s2, 64, lane, ks * 32);
            Aa[ks][3] = ld_af(v2, 64, lane, ks * 32);
        }
        f32x4 P = {}, Q = {}, V = {};
        #pragma unroll
        for (int ks = 0; ks < 2; ++ks)
            mf9(Aa[ks][0], Aa[ks][1], Aa[ks][2], Aa[ks][3], L3B[ks][0], L3B[ks][1], L3B[ks][2], P, Q, V);
        #pragma unroll
        for (int kk = 0; kk < KS_PER_CHUNK; ++kk)
            X[kk] = ld_bp(xiP, wave * 66 + kk, lane);
        int col = wave * 16 + c16;
        #pragma unroll
        for (int q = 0; q < 4; ++q) {
            int row = (lane >> 4) * 4 + q;
            float pre = P[q] + Q[q] + bb3;
            float hz = fmaxf(pre, 0.f);
            float vz = pre > 0.f ? V[q] : 0.f;
            zf[row * 68 + col] = hz;
            short s0, s1, s2;
            split3f(hz, s0, s1, s2);
            st_b16(zb0, 64, row, col, s0);
            st_b16(zb1, 64, row, col, s1);
            st_b16(zb2, 64, row, col, s2);
            zo[(size_t)(row0 + row) * DDIM + col] = hz;
            dz[(size_t)(row0 + row) * DDIM + col] = vz;
        }
        if (tid < 32) { int r = tid & 15; zf[r * 68 + 64 + (tid >> 4)] = (tid >> 4) ? 0.f : 1.f; }
    }
    __syncthreads();   // zf/zb ready; h1/h2 dead -> th may overwrite

    // ================= SINDy: 3 chunks of 704 (r6 structure) ========
    f32x4 sa0 = {}, sa1 = {};
#define BUILD(ch) { _Pragma("unroll") for (int g = 0; g < 11; ++g) { \
        int fl = tf44 + g * 4, fg = (ch) * CHUNK + fl; \
        int4 qa = *(const int4*)&pk[fg]; int4 qb = *(const int4*)&pk[fg + 2]; \
        float t0 = zf[tr * 68 + qa.x] * zf[tr * 68 + qa.y]; \
        float t1 = zf[tr * 68 + qa.z] * zf[tr * 68 + qa.w]; \
        float t2 = zf[tr * 68 + qb.x] * zf[tr * 68 + qb.y]; \
        float t3 = zf[tr * 68 + qb.z] * zf[tr * 68 + qb.w]; \
        short arr[4] = { f2b(t0), f2b(t1), f2b(t2), f2b(t3) }; \
        st_b64(th, 704, tr, fl, pk4(arr)); } }
#define SMF() { _Pragma("unroll") for (int kk = 0; kk < KS_PER_CHUNK; ++kk) { \
        bf16x8 a = ld_af(th, 704, lane, kk * 32); \
        if (kk & 1) sa1 = MFMA(a, X[kk], sa1); else sa0 = MFMA(a, X[kk], sa0); } }
#define ISX(ch) { _Pragma("unroll") for (int kk = 0; kk < KS_PER_CHUNK; ++kk) \
        X[kk] = ld_bp(xiP, wave * 66 + (ch) * KS_PER_CHUNK + kk, lane); }

    BUILD(0)
    __syncthreads();
    SMF() ISX(1)
    __syncthreads();
    BUILD(1)
    __syncthreads();
    SMF() ISX(2)
    __syncthreads();
    BUILD(2)
    __syncthreads();
    SMF()
#undef BUILD
#undef SMF
#undef ISX
    bf16x8 D1B[2][3];
    {
        f32x4 sacc = sa0 + sa1;
        #pragma unroll
        for (int ks = 0; ks < 2; ++ks) {
            int blk = wave * 2 + ks;
            D1B[ks][0] = ld_bp(Wp4, blk, lane);
            D1B[ks][1] = ld_bp(Wp4 + WSZ4, blk, lane);
            D1B[ks][2] = ld_bp(Wp4 + 2 * WSZ4, blk, lane);
        }
        int col = wave * 16 + c16;
        #pragma unroll
        for (int q = 0; q < 4; ++q) {
            int row = (lane >> 4) * 4 + q;
            float v = sacc[q];
            dzs[(size_t)(row0 + row) * DDIM + col] = v;
            st_b16(dzsb, 64, row, col, f2b(v));
        }
    }
    __syncthreads();   // dzsb ready; th dead -> g1 may overwrite

    // ================= decoder L1 (K=64) ========
    bf16x8 D2B[4][3];
    {
        bf16x8 Aa[2][4];
        #pragma unroll
        for (int ks = 0; ks < 2; ++ks) {
            Aa[ks][0] = ld_af(zb0, 64, lane, ks * 32);
            Aa[ks][1] = ld_af(zb1, 64, lane, ks * 32);
            Aa[ks][2] = ld_af(zb2, 64, lane, ks * 32);
            Aa[ks][3] = ld_af(dzsb, 64, lane, ks * 32);
        }
        #pragma unroll
        for (int cf = 0; cf < 2; ++cf)
            #pragma unroll
            for (int ks = 0; ks < 2; ++ks) {
                int blk = (wave * 2 + cf) * 2 + ks;
                D2B[cf * 2 + ks][0] = ld_bp(Wp5, blk, lane);
                D2B[cf * 2 + ks][1] = ld_bp(Wp5 + WSZ5, blk, lane);
                D2B[cf * 2 + ks][2] = ld_bp(Wp5 + 2 * WSZ5, blk, lane);
            }
        f32x4 P = {}, Q = {}, V = {};
        #pragma unroll
        for (int ks = 0; ks < 2; ++ks)
            mf9(Aa[ks][0], Aa[ks][1], Aa[ks][2], Aa[ks][3], D1B[ks][0], D1B[ks][1], D1B[ks][2], P, Q, V);
        epi_store(g1s0, g1s1, g1s2, u1, 64, lane, wave * 16 + c16, P, Q, V, bD1);
    }
    __syncthreads();

    // ================= decoder L2 (K=64, N=128) ========
    {
        bf16x8 Aa[2][4];
        #pragma unroll
        for (int ks = 0; ks < 2; ++ks) {
            Aa[ks][0] = ld_af(g1s0, 64, lane, ks * 32);
            Aa[ks][1] = ld_af(g1s1, 64, lane, ks * 32);
            Aa[ks][2] = ld_af(g1s2, 64, lane, ks * 32);
            Aa[ks][3] = ld_af(u1, 64, lane, ks * 32);
        }
        f32x4 P[2] = {}, Q[2] = {}, V[2] = {};
        #pragma unroll
        for (int cf = 0; cf < 2; ++cf)
            #pragma unroll
            for (int ks = 0; ks < 2; ++ks)
                mf9(Aa[ks][0], Aa[ks][1], Aa[ks][2], Aa[ks][3],
                    D2B[cf * 2 + ks][0], D2B[cf * 2 + ks][1], D2B[cf * 2 + ks][2],
                    P[cf], Q[cf], V[cf]);
        #pragma unroll
        for (int cf = 0; cf < 2; ++cf) {
            int col = wave * 32 + cf * 16 + c16;
            epi_store(g2s0, g2s1, g2s2, u2, 128, lane, col, P[cf], Q[cf], V[cf], bD2[cf]);
        }
    }
    __syncthreads();

    // ================= decoder L3 (K=128, N=512): DMA pipeline, depth 4 ====
    bf16x8 Ax0, Ax1, Ax2, Axv;
    const char* w6ac = (const char*)Wp6;
    const char* w6bc = (const char*)(Wp6 + WSZ6);
    const char* w6cc = (const char*)(Wp6 + 2 * WSZ6);
#define D3SLOT(d) (unsigned)(40960 + wave * 12288 + (d) * 3072)
#define D3ISS(h, s) { unsigned sb = D3SLOT((s) & 3); \
        int bo = ((wave * 8 + (h) * 4 + ((s) & 3)) * 4 + ((s) >> 2)) * 1024 + lane16; \
        GLL(w6ac + bo, sb); GLL(w6bc + bo, sb + 1024); GLL(w6cc + bo, sb + 2048); }
#define D3STEP(h, s, WN, Pa, Qa, Va) { waitv<WN>(); \
        if (((s) & 3) == 0) { int ks = (s) >> 2; \
            Ax0 = ld_af(g2s0, 128, lane, ks * 32); Ax1 = ld_af(g2s1, 128, lane, ks * 32); \
            Ax2 = ld_af(g2s2, 128, lane, ks * 32); Axv = ld_af(u2, 128, lane, ks * 32); } \
        { unsigned sb = D3SLOT((s) & 3); \
          bf16x8 c0 = *(const bf16x8*)&lds[sb + lane16]; \
          bf16x8 c1 = *(const bf16x8*)&lds[sb + 1024 + lane16]; \
          bf16x8 c2 = *(const bf16x8*)&lds[sb + 2048 + lane16]; \
          mf9(Ax0, Ax1, Ax2, Axv, c0, c1, c2, Pa[(s) & 3], Qa[(s) & 3], Va[(s) & 3]); } \
        __builtin_amdgcn_sched_barrier(0); \
        if ((s) + 4 < 16) D3ISS(h, (s) + 4) }
#define D3EPI(h, P_, Q_, V_) { _Pragma("unroll") for (int cf = 0; cf < 4; ++cf) { \
        int col = wave * 128 + (h) * 64 + cf * 16 + c16; \
        float bb = bD3[(h) * 4 + cf]; \
        _Pragma("unroll") for (int q = 0; q < 4; ++q) { \
            int row = (lane >> 4) * 4 + q; \
            float pre = P_[cf][q] + Q_[cf][q] + bb; \
            xh[(size_t)(row0 + row) * IN_DIM + col] = fmaxf(pre, 0.f); \
            dxh[(size_t)(row0 + row) * IN_DIM + col] = pre > 0.f ? V_[cf][q] : 0.f; } } }

    {
        f32x4 P[4] = {}, Q[4] = {}, V[4] = {};
        D3ISS(0, 0) D3ISS(0, 1) D3ISS(0, 2) D3ISS(0, 3)
        D3STEP(0, 0, 9, P, Q, V)  D3STEP(0, 1, 9, P, Q, V)  D3STEP(0, 2, 9, P, Q, V)  D3STEP(0, 3, 9, P, Q, V)
        D3STEP(0, 4, 9, P, Q, V)  D3STEP(0, 5, 9, P, Q, V)  D3STEP(0, 6, 9, P, Q, V)  D3STEP(0, 7, 9, P, Q, V)
        D3STEP(0, 8, 9, P, Q, V)  D3STEP(0, 9, 9, P, Q, V)  D3STEP(0, 10, 9, P, Q, V) D3STEP(0, 11, 9, P, Q, V)
        D3STEP(0, 12, 9, P, Q, V) D3STEP(0, 13, 6, P, Q, V) D3STEP(0, 14, 3, P, Q, V) D3STEP(0, 15, 0, P, Q, V)
        D3EPI(0, P, Q, V)
    }
    {
        f32x4 P[4] = {}, Q[4] = {}, V[4] = {};
        D3ISS(1, 0) D3ISS(1, 1) D3ISS(1, 2) D3ISS(1, 3)
        D3STEP(1, 0, 9, P, Q, V)  D3STEP(1, 1, 9, P, Q, V)  D3STEP(1, 2, 9, P, Q, V)  D3STEP(1, 3, 9, P, Q, V)
        D3STEP(1, 4, 9, P, Q, V)  D3STEP(1, 5, 9, P, Q, V)  D3STEP(1, 6, 9, P, Q, V)  D3STEP(1, 7, 9, P, Q, V)
        D3STEP(1, 8, 9, P, Q, V)  D3STEP(1, 9, 9, P, Q, V)  D3STEP(1, 10, 9, P, Q, V) D3STEP(1, 11, 9, P, Q, V)
        D3STEP(1, 12, 9, P, Q, V) D3STEP(1, 13, 6, P, Q, V) D3STEP(1, 14, 3, P, Q, V) D3STEP(1, 15, 0, P, Q, V)
        D3EPI(1, P, Q, V)
    }
#undef D3ISS
#undef D3STEP
#undef D3EPI
#undef D3SLOT
#undef GLL
}

// =====================================================================
extern "C" void kernel_launch(void* const* d_in, const int* in_sizes, int n_in,
                              void* d_out, int out_size, void* d_ws, size_t ws_size,
                              hipStream_t stream)
{
    const float* x    = (const float*)d_in[0];
    const float* xdot = (const float*)d_in[1];
    const float* We1  = (const float*)d_in[2];
    const float* be1  = (const float*)d_in[3];
    const float* We2  = (const float*)d_in[4];
    const float* be2  = (const float*)d_in[5];
    const float* We3  = (const float*)d_in[6];
    const float* be3  = (const float*)d_in[7];
    const float* Wd1  = (const float*)d_in[8];
    const float* bd1  = (const float*)d_in[9];
    const float* Wd2  = (const float*)d_in[10];
    const float* bd2  = (const float*)d_in[11];
    const float* Wd3  = (const float*)d_in[12];
    const float* bd3  = (const float*)d_in[13];
    const float* XI   = (const float*)d_in[14];
    const float* XIm  = (const float*)d_in[15];

    float* out = (float*)d_out;
    float* xh  = out;
    float* dxh = out + (size_t)BATCH * IN_DIM;
    float* zo  = dxh + (size_t)BATCH * IN_DIM;
    float* dz  = zo + (size_t)BATCH * DDIM;
    float* dzs = dz + (size_t)BATCH * DDIM;

    int2*  pk  = (int2*)d_ws;
    short* Wp1 = (short*)(pk + NFPAD);
    short* Wp2 = Wp1 + 3 * WSZ1;
    short* Wp3 = Wp2 + 3 * WSZ2;
    short* Wp4 = Wp3 + 3 * WSZ3;
    short* Wp5 = Wp4 + 3 * WSZ4;
    short* Wp6 = Wp5 + 3 * WSZ5;
    short* xiP = Wp6 + 3 * WSZ6;

    initk<<<1024, 256, 0, stream>>>(x, xdot, We1, We2, We3, Wd1, Wd2, Wd3, XI, XIm,
                                    xh, dxh, Wp1, Wp2, Wp3, Wp4, Wp5, Wp6, xiP, pk);
    fused<<<BATCH / 16, 256, 0, stream>>>(be1, be2, be3, bd1, bd2, bd3,
                                          Wp1, Wp2, Wp3, Wp4, Wp5, Wp6, xiP, pk,
                                          xh, dxh, zo, dz, dzs);
}